// Round 10
// baseline (330.374 us; speedup 1.0000x reference)
//
#include <hip/hip_runtime.h>
#include <hip/hip_fp16.h>

#define NN 100000
#define NE 1600000
#define NG 512
#define NC 16
#define HC 32  // histogram copies

static inline int cdiv(long long a, int b) { return (int)((a + b - 1) / b); }

__device__ __forceinline__ unsigned int pack_f16(float x, float y) {
  __half2 h = __floats2half2_rn(x, y);
  return *reinterpret_cast<unsigned int*>(&h);
}
__device__ __forceinline__ float2 unpack_f16(unsigned int u) {
  __half2 h = *reinterpret_cast<__half2*>(&u);
  return __half22float2(h);
}

__global__ void k_zero_i(int* p, int n) {
  int i = blockIdx.x * blockDim.x + threadIdx.x;
  if (i < n) p[i] = 0;
}

// HC-way replicated in-degree histogram; rank[e] = arrival order within (d,c) bucket
__global__ void k_hist8(const int* __restrict__ dst, int* __restrict__ cnt,
                        int* __restrict__ rank) {
  int e = blockIdx.x * blockDim.x + threadIdx.x;
  if (e < NE) rank[e] = atomicAdd(&cnt[dst[e] * HC + (e & (HC - 1))], 1);
}

// sum copies -> count; copies -> per-copy exclusive prefix (in place); dinv
__global__ void k_reduce(int* __restrict__ cnt, int* __restrict__ count,
                         float* __restrict__ dinv) {
  int i = blockIdx.x * blockDim.x + threadIdx.x;
  if (i >= NN) return;
  int s = 0;
#pragma unroll
  for (int c = 0; c < HC; ++c) {
    int v = cnt[i * HC + c];
    cnt[i * HC + c] = s;
    s += v;
  }
  count[i] = s;
  dinv[i] = rsqrtf((float)(s + 1));  // +1 self loop
}

// graph boundaries from sorted batch: gstart[g] = first node index with batch >= g
__global__ void k_bounds(const int* __restrict__ batch, int* __restrict__ gstart) {
  int i = blockIdx.x * blockDim.x + threadIdx.x;
  if (i > NN) return;
  int b = (i < NN) ? batch[i] : NG;
  int bp = (i > 0) ? batch[i - 1] : -1;
  for (int g = bp + 1; g <= b; ++g) gstart[g] = i;
}

// exclusive scan, 256/block; bsum gets block totals
__global__ void k_scan1(const int* __restrict__ in, int* __restrict__ out,
                        int* __restrict__ bsum, int n) {
  __shared__ int s[256];
  int t = threadIdx.x, i = blockIdx.x * 256 + t;
  int v = (i < n) ? in[i] : 0;
  s[t] = v;
  __syncthreads();
  for (int d = 1; d < 256; d <<= 1) {
    int a = (t >= d) ? s[t - d] : 0;
    __syncthreads();
    s[t] += a;
    __syncthreads();
  }
  if (i < n) out[i] = s[t] - v;  // exclusive
  if (t == 255) bsum[blockIdx.x] = s[255];
}

// single-block exclusive scan over <=512 values
__global__ void k_scan2(const int* __restrict__ in, int* __restrict__ out, int nb) {
  __shared__ int s[512];
  int t = threadIdx.x;
  int v = (t < nb) ? in[t] : 0;
  s[t] = v;
  __syncthreads();
  for (int d = 1; d < 512; d <<= 1) {
    int a = (t >= d) ? s[t - d] : 0;
    __syncthreads();
    s[t] += a;
    __syncthreads();
  }
  if (t < nb) out[t] = s[t] - v;
}

// finalize offs; convert cnt per-copy prefixes to ABSOLUTE bucket starts (in place)
__global__ void k_scan3(int* __restrict__ offs, const int* __restrict__ bpref,
                        int* __restrict__ cnt) {
  int i = blockIdx.x * blockDim.x + threadIdx.x;
  if (i >= NN) return;
  int run = offs[i] + bpref[i >> 8];
  offs[i] = run;
#pragma unroll
  for (int c = 0; c < HC; ++c) cnt[i * HC + c] += run;
}

// scatter edges into CSR slots; NO atomics (rank precomputed, absolute bucket starts)
__global__ void k_fill(const int* __restrict__ src, const int* __restrict__ dst,
                       const int* __restrict__ cnt, const int* __restrict__ rank,
                       const float* __restrict__ dinv, int2* __restrict__ csr) {
  int e = blockIdx.x * blockDim.x + threadIdx.x;
  if (e >= NE) return;
  int s = src[e], d = dst[e];
  int pos = cnt[d * HC + (e & (HC - 1))] + rank[e];
  csr[pos] = make_int2(s, __float_as_int(dinv[s] * dinv[d]));
}

// gather-reduce aggregation (fp32 rows), int2 csr. BR: fused bias+relu.
template <int F, int LPN, bool BR>
__global__ void k_agg(const float* __restrict__ h, const int2* __restrict__ csr,
                      const int* __restrict__ offs, const int* __restrict__ count,
                      const float* __restrict__ dinv, const float* __restrict__ bias,
                      float* __restrict__ out) {
  int wave = threadIdx.x >> 6, lane = threadIdx.x & 63;
  const int NPW = 64 / LPN;  // nodes per wave
  int i = (blockIdx.x * 4 + wave) * NPW + ((LPN == 64) ? 0 : (lane >> 4));
  int f = lane & (LPN - 1);
  if (i >= NN) return;
  int off = offs[i], cnt = count[i];
  float acc0 = 0.f, acc1 = 0.f, acc2 = 0.f, acc3 = 0.f;
  int j = 0;
  for (; j + 3 < cnt; j += 4) {
    int2 p0 = csr[off + j];
    int2 p1 = csr[off + j + 1];
    int2 p2 = csr[off + j + 2];
    int2 p3 = csr[off + j + 3];
    acc0 += h[(size_t)p0.x * F + f] * __int_as_float(p0.y);
    acc1 += h[(size_t)p1.x * F + f] * __int_as_float(p1.y);
    acc2 += h[(size_t)p2.x * F + f] * __int_as_float(p2.y);
    acc3 += h[(size_t)p3.x * F + f] * __int_as_float(p3.y);
  }
  for (; j < cnt; ++j) {
    int2 p0 = csr[off + j];
    acc0 += h[(size_t)p0.x * F + f] * __int_as_float(p0.y);
  }
  float di = dinv[i];
  acc0 += h[(size_t)i * F + f] * di * di;  // self loop
  float v = (acc0 + acc1) + (acc2 + acc3);
  if (BR) v = fmaxf(v + bias[f], 0.f);
  out[(size_t)i * F + f] = v;
}

// fp16 gather-reduce for F=64: 32 lanes/node, 2 packed features/lane; fp16 output
__global__ void k_agg_b64(const unsigned int* __restrict__ h, const int2* __restrict__ csr,
                          const int* __restrict__ offs, const int* __restrict__ count,
                          const float* __restrict__ dinv, unsigned int* __restrict__ out) {
  int wave = threadIdx.x >> 6, lane = threadIdx.x & 63;
  int i = (blockIdx.x * 4 + wave) * 2 + (lane >> 5);
  int fp = lane & 31;  // feature pair
  if (i >= NN) return;
  int off = offs[i], cnt = count[i];
  float a0 = 0.f, a1 = 0.f, b0 = 0.f, b1 = 0.f;
  float c0 = 0.f, c1 = 0.f, d0 = 0.f, d1 = 0.f;
  int j = 0;
  for (; j + 3 < cnt; j += 4) {
    int2 p0 = csr[off + j], p1 = csr[off + j + 1];
    int2 p2 = csr[off + j + 2], p3 = csr[off + j + 3];
    float2 f0 = unpack_f16(h[(size_t)p0.x * 32 + fp]);
    float2 f1 = unpack_f16(h[(size_t)p1.x * 32 + fp]);
    float2 f2 = unpack_f16(h[(size_t)p2.x * 32 + fp]);
    float2 f3 = unpack_f16(h[(size_t)p3.x * 32 + fp]);
    float w0 = __int_as_float(p0.y), w1 = __int_as_float(p1.y);
    float w2 = __int_as_float(p2.y), w3 = __int_as_float(p3.y);
    a0 += f0.x * w0; a1 += f0.y * w0;
    b0 += f1.x * w1; b1 += f1.y * w1;
    c0 += f2.x * w2; c1 += f2.y * w2;
    d0 += f3.x * w3; d1 += f3.y * w3;
  }
  for (; j < cnt; ++j) {
    int2 p0 = csr[off + j];
    float2 f0 = unpack_f16(h[(size_t)p0.x * 32 + fp]);
    float w0 = __int_as_float(p0.y);
    a0 += f0.x * w0; a1 += f0.y * w0;
  }
  float di = dinv[i];
  float2 fs = unpack_f16(h[(size_t)i * 32 + fp]);
  a0 += fs.x * di * di; a1 += fs.y * di * di;
  out[(size_t)i * 32 + fp] = pack_f16((a0 + b0) + (c0 + d0), (a1 + b1) + (c1 + d1));
}

// out[i,o] = a[i,:]@W[:,o] (+bias, relu if BR)
template <int FIN, int FOUT, bool BR>
__global__ void k_dense(const float* __restrict__ a, const float* __restrict__ W,
                        const float* __restrict__ b, float* __restrict__ out, int n) {
  __shared__ float sW[FIN * FOUT];
  __shared__ float sb[FOUT];
  for (int t = threadIdx.x; t < FIN * FOUT; t += blockDim.x) sW[t] = W[t];
  if (BR)
    for (int t = threadIdx.x; t < FOUT; t += blockDim.x) sb[t] = b[t];
  __syncthreads();
  int idx = blockIdx.x * blockDim.x + threadIdx.x;
  int i = idx / FOUT, o = idx % FOUT;
  if (i >= n) return;
  float acc = BR ? sb[o] : 0.f;
#pragma unroll
  for (int k = 0; k < FIN; ++k) acc += a[(size_t)i * FIN + k] * sW[k * FOUT + o];
  out[idx] = BR ? fmaxf(acc, 0.0f) : acc;
}

// dense 16->64 with bias+relu, fp16-packed output (2 outputs/thread)
__global__ void k_dense2_b(const float* __restrict__ a, const float* __restrict__ W,
                           const float* __restrict__ b, unsigned int* __restrict__ out,
                           int n) {
  __shared__ float sW[16 * 64];
  __shared__ float sb[64];
  for (int t = threadIdx.x; t < 16 * 64; t += blockDim.x) sW[t] = W[t];
  for (int t = threadIdx.x; t < 64; t += blockDim.x) sb[t] = b[t];
  __syncthreads();
  int idx = blockIdx.x * blockDim.x + threadIdx.x;
  int i = idx >> 5, op = idx & 31;
  if (i >= n) return;
  float acc0 = sb[2 * op], acc1 = sb[2 * op + 1];
#pragma unroll
  for (int k = 0; k < 16; ++k) {
    float av = a[(size_t)i * 16 + k];
    acc0 += av * sW[k * 64 + 2 * op];
    acc1 += av * sW[k * 64 + 2 * op + 1];
  }
  out[(size_t)i * 32 + op] = pack_f16(fmaxf(acc0, 0.f), fmaxf(acc1, 0.f));
}

// fused dense3(64->128)+relu+segmented mean-pool; NO LDS; fp16 input rows.
// 2 waves per 16-node run; wave-uniform row reads; W3 column in 64 VGPRs.
#define P4_NPW 16  // nodes per wave-pair run
__global__ __launch_bounds__(256) void k_dense3_pool4(
    const unsigned int* __restrict__ t3h, const float* __restrict__ W3,
    const float* __restrict__ b3, const int* __restrict__ batch,
    float* __restrict__ gsum) {
  int wu = blockIdx.x * 4 + (threadIdx.x >> 6);  // global wave unit
  int lane = threadIdx.x & 63;
  int run = wu >> 1;
  int o = (wu & 1) * 64 + lane;  // output feature
  int n0 = run * P4_NPW;
  if (n0 >= NN) return;
  float wcol[64];
#pragma unroll
  for (int k = 0; k < 64; ++k) wcol[k] = W3[k * 128 + o];
  float bias = b3[o];
  float acc = 0.f;
  int curg = -1;
#pragma unroll 1
  for (int j = 0; j < P4_NPW; ++j) {
    int n = n0 + j;
    if (n >= NN) break;
    int nu = __builtin_amdgcn_readfirstlane(n);
    const uint4* row = (const uint4*)(t3h + (size_t)nu * 32);
    float v = bias;
#pragma unroll
    for (int q = 0; q < 8; ++q) {
      uint4 r = row[q];  // wave-uniform address, 8 halves
      float2 p0 = unpack_f16(r.x), p1 = unpack_f16(r.y);
      float2 p2 = unpack_f16(r.z), p3 = unpack_f16(r.w);
      v += p0.x * wcol[8 * q] + p0.y * wcol[8 * q + 1] + p1.x * wcol[8 * q + 2] +
           p1.y * wcol[8 * q + 3] + p2.x * wcol[8 * q + 4] + p2.y * wcol[8 * q + 5] +
           p3.x * wcol[8 * q + 6] + p3.y * wcol[8 * q + 7];
    }
    int g = batch[nu];
    if (g != curg) {
      if (curg >= 0) atomicAdd(&gsum[curg * 128 + o], acc);
      curg = g;
      acc = 0.f;
    }
    acc += fmaxf(v, 0.f);
  }
  if (curg >= 0) atomicAdd(&gsum[curg * 128 + o], acc);
}

// one wave per graph: logits = (gsum/cnt) @ Wl + bl; log_softmax over 16 classes
__global__ void k_head(const float* __restrict__ gsum, const int* __restrict__ gstart,
                       const float* __restrict__ Wl, const float* __restrict__ bl,
                       float* __restrict__ out) {
  int wave = threadIdx.x >> 6, lane = threadIdx.x & 63;
  int g = blockIdx.x * 4 + wave;
  if (g >= NG) return;
  int c = lane & 15, part = lane >> 4;
  float acc = 0.f;
#pragma unroll
  for (int kk = 0; kk < 32; ++kk) {
    int k = part * 32 + kk;
    acc += gsum[g * 128 + k] * Wl[k * NC + c];
  }
  acc += __shfl_xor(acc, 16);
  acc += __shfl_xor(acc, 32);
  int cnt = gstart[g + 1] - gstart[g];
  float inv = 1.0f / (float)max(cnt, 1);
  float logit = acc * inv + bl[c];
  float m = logit;
#pragma unroll
  for (int d = 1; d < 16; d <<= 1) m = fmaxf(m, __shfl_xor(m, d));
  float ex = expf(logit - m), s = ex;
#pragma unroll
  for (int d = 1; d < 16; d <<= 1) s += __shfl_xor(s, d);
  if (lane < 16) out[g * NC + lane] = logit - m - logf(s);
}

extern "C" void kernel_launch(void* const* d_in, const int* in_sizes, int n_in,
                              void* d_out, int out_size, void* d_ws, size_t ws_size,
                              hipStream_t stream) {
  const float* x = (const float*)d_in[0];
  const int* ei = (const int*)d_in[1];
  const int* batch = (const int*)d_in[2];
  const float* W1 = (const float*)d_in[3];
  const float* b1 = (const float*)d_in[4];
  const float* W2 = (const float*)d_in[5];
  const float* b2 = (const float*)d_in[6];
  const float* W3 = (const float*)d_in[7];
  const float* b3 = (const float*)d_in[8];
  const float* Wl = (const float*)d_in[9];
  const float* bl = (const float*)d_in[10];
  const int* src = ei;
  const int* dst = ei + NE;

  // workspace layout; zero range = [cnt, gsum] contiguous; total ~65.5 MB
  int* cnt = (int*)d_ws;                    // NN*HC (12.8 MB)
  float* gsum = (float*)(cnt + NN * HC);    // NG*128
  int* count = (int*)(gsum + NG * 128);     // NN
  int* offs = count + NN;                   // NN
  int* gstart = offs + NN;                  // NG+2
  int* bsum = gstart + NG + 2;              // 1024
  int* bpref = bsum + 1024;                 // 1024
  float* dinv = (float*)(bpref + 1024);     // NN
  int2* csr = (int2*)(dinv + NN);           // NE int2 (8B aligned)
  float* t1 = (float*)(csr + NE);           // NN*16 (aliases rank until k_fill done)
  float* h1 = t1 + (size_t)NN * 16;         // NN*16
  unsigned int* h2b = (unsigned int*)(h1 + (size_t)NN * 16);   // NN*32 (fp16x2)
  unsigned int* t3h = h2b + (size_t)NN * 32;                   // NN*32 (fp16x2)
  int* rank = (int*)t1;  // NE ints == NN*16 slots; dead before t1 is written

  const int B = 256;
  const int NB_SCAN = cdiv(NN, 256);  // 391
  const int n_zero_elems = NN * HC + NG * 128;

  // CSR build + norms + graph bounds
  k_zero_i<<<cdiv(n_zero_elems, B), B, 0, stream>>>(cnt, n_zero_elems);
  k_hist8<<<cdiv(NE, B), B, 0, stream>>>(dst, cnt, rank);
  k_bounds<<<cdiv(NN + 1, B), B, 0, stream>>>(batch, gstart);
  k_reduce<<<cdiv(NN, B), B, 0, stream>>>(cnt, count, dinv);
  k_scan1<<<NB_SCAN, 256, 0, stream>>>(count, offs, bsum, NN);
  k_scan2<<<1, 512, 0, stream>>>(bsum, bpref, NB_SCAN);
  k_scan3<<<cdiv(NN, B), B, 0, stream>>>(offs, bpref, cnt);
  k_fill<<<cdiv(NE, B), B, 0, stream>>>(src, dst, cnt, rank, dinv, csr);

  // layer 1 (transform-first): t1 = x@W1; h1 = relu(agg(t1)+b1)
  k_dense<13, 16, false><<<cdiv((long long)NN * 16, B), B, 0, stream>>>(x, W1, b1, t1, NN);
  k_agg<16, 16, true><<<cdiv(NN, 16), B, 0, stream>>>(t1, csr, offs, count, dinv, b1, h1);
  // layer 2: t2 = agg(h1) (reuse t1); h2 = fp16(relu(t2@W2+b2))
  k_agg<16, 16, false><<<cdiv(NN, 16), B, 0, stream>>>(h1, csr, offs, count, dinv, nullptr, t1);
  k_dense2_b<<<cdiv((long long)NN * 32, B), B, 0, stream>>>(t1, W2, b2, h2b, NN);
  // layer 3: t3h = agg_fp16(h2); fused dense(64->128)+relu+pool (no LDS, fp16 rows)
  k_agg_b64<<<cdiv(NN, 8), B, 0, stream>>>(h2b, csr, offs, count, dinv, t3h);
  {
    int runs = cdiv(NN, P4_NPW);
    k_dense3_pool4<<<cdiv(runs * 2, 4), 256, 0, stream>>>(t3h, W3, b3, batch, gsum);
  }

  // head
  k_head<<<NG / 4, B, 0, stream>>>(gsum, gstart, Wl, bl, (float*)d_out);
}

// Round 11
// 252.980 us; speedup vs baseline: 1.3059x; 1.3059x over previous
//
#include <hip/hip_runtime.h>
#include <hip/hip_fp16.h>

#define NN 100000
#define NE 1600000
#define NG 512
#define NC 16
#define NBUK 391  // coarse buckets = cdiv(NN,256), bucket = dst>>8
#define EPB 8192  // edges per phase-1 block
#define NB1 196   // cdiv(NE, EPB)

static inline int cdiv(long long a, int b) { return (int)((a + b - 1) / b); }

__device__ __forceinline__ unsigned int pack_f16(float x, float y) {
  __half2 h = __floats2half2_rn(x, y);
  return *reinterpret_cast<unsigned int*>(&h);
}
__device__ __forceinline__ float2 unpack_f16(unsigned int u) {
  __half2 h = *reinterpret_cast<__half2*>(&u);
  return __half22float2(h);
}

__global__ void k_zero_i(int* p, int n) {
  int i = blockIdx.x * blockDim.x + threadIdx.x;
  if (i < n) p[i] = 0;
}

// p1a: per-block coarse histogram (dst>>8) -> bcnt[bucket*NB1 + blk]  (LDS atomics only)
__global__ void k_p1a(const int* __restrict__ dst, int* __restrict__ bcnt) {
  __shared__ int sh[NBUK];
  int t = threadIdx.x, blk = blockIdx.x;
  for (int u = t; u < NBUK; u += 256) sh[u] = 0;
  __syncthreads();
  int e0 = blk * EPB;
#pragma unroll
  for (int k = 0; k < EPB / 256; ++k) {
    int e = e0 + k * 256 + t;
    if (e < NE) atomicAdd(&sh[dst[e] >> 8], 1);
  }
  __syncthreads();
  for (int u = t; u < NBUK; u += 256) bcnt[u * NB1 + blk] = sh[u];
}

// p1b: scatter edges into coarse-bucket partitions; packed = (dst&255)<<24 | src
__global__ void k_p1b(const int* __restrict__ src, const int* __restrict__ dst,
                      const int* __restrict__ bpos, unsigned int* __restrict__ packed) {
  __shared__ int sbase[NBUK];
  int t = threadIdx.x, blk = blockIdx.x;
  for (int u = t; u < NBUK; u += 256) sbase[u] = bpos[u * NB1 + blk];
  __syncthreads();
  int e0 = blk * EPB;
#pragma unroll
  for (int k = 0; k < EPB / 256; ++k) {
    int e = e0 + k * 256 + t;
    if (e < NE) {
      int d = dst[e];
      int pos = atomicAdd(&sbase[d >> 8], 1);  // LDS returning atomic
      packed[pos] = ((unsigned int)(d & 255) << 24) | (unsigned int)src[e];
    }
  }
}

// p2: per-bucket fine counting sort by dst-low8; emits count/offs/dinv + src-only csr
__global__ void k_p2(const unsigned int* __restrict__ packed, const int* __restrict__ bpos,
                     int* __restrict__ count, int* __restrict__ offs,
                     float* __restrict__ dinv, int* __restrict__ csr) {
  __shared__ int sh[256], sc[256], cur[256];
  int t = threadIdx.x, u = blockIdx.x;
  int s0 = bpos[u * NB1];
  int s1 = (u + 1 < NBUK) ? bpos[(u + 1) * NB1] : NE;
  sh[t] = 0;
  __syncthreads();
  for (int e = s0 + t; e < s1; e += 256) atomicAdd(&sh[packed[e] >> 24], 1);
  __syncthreads();
  sc[t] = sh[t];
  __syncthreads();
  for (int d = 1; d < 256; d <<= 1) {
    int a = (t >= d) ? sc[t - d] : 0;
    __syncthreads();
    sc[t] += a;
    __syncthreads();
  }
  int excl = sc[t] - sh[t];
  int node = u * 256 + t;
  if (node < NN) {
    count[node] = sh[t];
    offs[node] = s0 + excl;
    dinv[node] = rsqrtf((float)(sh[t] + 1));  // +1 self loop
  }
  cur[t] = s0 + excl;
  __syncthreads();
  for (int e = s0 + t; e < s1; e += 256) {
    unsigned int p = packed[e];
    int pos = atomicAdd(&cur[p >> 24], 1);  // LDS returning atomic
    csr[pos] = (int)(p & 0xFFFFFFu >> 0 & 0x00FFFFFFu);
  }
}

// graph boundaries from sorted batch: gstart[g] = first node index with batch >= g
__global__ void k_bounds(const int* __restrict__ batch, int* __restrict__ gstart) {
  int i = blockIdx.x * blockDim.x + threadIdx.x;
  if (i > NN) return;
  int b = (i < NN) ? batch[i] : NG;
  int bp = (i > 0) ? batch[i - 1] : -1;
  for (int g = bp + 1; g <= b; ++g) gstart[g] = i;
}

// exclusive scan, 256/block; bsum gets block totals
__global__ void k_scan1(const int* __restrict__ in, int* __restrict__ out,
                        int* __restrict__ bsum, int n) {
  __shared__ int s[256];
  int t = threadIdx.x, i = blockIdx.x * 256 + t;
  int v = (i < n) ? in[i] : 0;
  s[t] = v;
  __syncthreads();
  for (int d = 1; d < 256; d <<= 1) {
    int a = (t >= d) ? s[t - d] : 0;
    __syncthreads();
    s[t] += a;
    __syncthreads();
  }
  if (i < n) out[i] = s[t] - v;  // exclusive
  if (t == 255) bsum[blockIdx.x] = s[255];
}

// single-block exclusive scan over <=512 values
__global__ void k_scan2(const int* __restrict__ in, int* __restrict__ out, int nb) {
  __shared__ int s[512];
  int t = threadIdx.x;
  int v = (t < nb) ? in[t] : 0;
  s[t] = v;
  __syncthreads();
  for (int d = 1; d < 512; d <<= 1) {
    int a = (t >= d) ? s[t - d] : 0;
    __syncthreads();
    s[t] += a;
    __syncthreads();
  }
  if (t < nb) out[t] = s[t] - v;
}

__global__ void k_scan3b(int* __restrict__ a, const int* __restrict__ bpref, int n) {
  int i = blockIdx.x * blockDim.x + threadIdx.x;
  if (i < n) a[i] += bpref[i >> 8];
}

// gather-reduce aggregation (fp32 rows), src-only csr, inline weights. BR: bias+relu.
template <int F, int LPN, bool BR>
__global__ void k_agg(const float* __restrict__ h, const int* __restrict__ csr,
                      const int* __restrict__ offs, const int* __restrict__ count,
                      const float* __restrict__ dinv, const float* __restrict__ bias,
                      float* __restrict__ out) {
  int wave = threadIdx.x >> 6, lane = threadIdx.x & 63;
  const int NPW = 64 / LPN;  // nodes per wave
  int i = (blockIdx.x * 4 + wave) * NPW + ((LPN == 64) ? 0 : (lane >> 4));
  int f = lane & (LPN - 1);
  if (i >= NN) return;
  int off = offs[i], cnt = count[i];
  float di = dinv[i];
  float acc0 = 0.f, acc1 = 0.f, acc2 = 0.f, acc3 = 0.f;
  int j = 0;
  for (; j + 3 < cnt; j += 4) {
    int s0 = csr[off + j], s1 = csr[off + j + 1];
    int s2 = csr[off + j + 2], s3 = csr[off + j + 3];
    float w0 = dinv[s0] * di, w1 = dinv[s1] * di;
    float w2 = dinv[s2] * di, w3 = dinv[s3] * di;
    acc0 += h[(size_t)s0 * F + f] * w0;
    acc1 += h[(size_t)s1 * F + f] * w1;
    acc2 += h[(size_t)s2 * F + f] * w2;
    acc3 += h[(size_t)s3 * F + f] * w3;
  }
  for (; j < cnt; ++j) {
    int s0 = csr[off + j];
    acc0 += h[(size_t)s0 * F + f] * (dinv[s0] * di);
  }
  acc0 += h[(size_t)i * F + f] * di * di;  // self loop
  float v = (acc0 + acc1) + (acc2 + acc3);
  if (BR) v = fmaxf(v + bias[f], 0.f);
  out[(size_t)i * F + f] = v;
}

// fp16 gather-reduce for F=64: 32 lanes/node, 2 packed features/lane; fp16 out; inline w
__global__ void k_agg_b64(const unsigned int* __restrict__ h, const int* __restrict__ csr,
                          const int* __restrict__ offs, const int* __restrict__ count,
                          const float* __restrict__ dinv, unsigned int* __restrict__ out) {
  int wave = threadIdx.x >> 6, lane = threadIdx.x & 63;
  int i = (blockIdx.x * 4 + wave) * 2 + (lane >> 5);
  int fp = lane & 31;  // feature pair
  if (i >= NN) return;
  int off = offs[i], cnt = count[i];
  float di = dinv[i];
  float a0 = 0.f, a1 = 0.f, b0 = 0.f, b1 = 0.f;
  float c0 = 0.f, c1 = 0.f, d0 = 0.f, d1 = 0.f;
  int j = 0;
  for (; j + 3 < cnt; j += 4) {
    int s0 = csr[off + j], s1 = csr[off + j + 1];
    int s2 = csr[off + j + 2], s3 = csr[off + j + 3];
    float2 f0 = unpack_f16(h[(size_t)s0 * 32 + fp]);
    float2 f1 = unpack_f16(h[(size_t)s1 * 32 + fp]);
    float2 f2 = unpack_f16(h[(size_t)s2 * 32 + fp]);
    float2 f3 = unpack_f16(h[(size_t)s3 * 32 + fp]);
    float w0 = dinv[s0] * di, w1 = dinv[s1] * di;
    float w2 = dinv[s2] * di, w3 = dinv[s3] * di;
    a0 += f0.x * w0; a1 += f0.y * w0;
    b0 += f1.x * w1; b1 += f1.y * w1;
    c0 += f2.x * w2; c1 += f2.y * w2;
    d0 += f3.x * w3; d1 += f3.y * w3;
  }
  for (; j < cnt; ++j) {
    int s0 = csr[off + j];
    float2 f0 = unpack_f16(h[(size_t)s0 * 32 + fp]);
    float w0 = dinv[s0] * di;
    a0 += f0.x * w0; a1 += f0.y * w0;
  }
  float2 fs = unpack_f16(h[(size_t)i * 32 + fp]);
  a0 += fs.x * di * di; a1 += fs.y * di * di;
  out[(size_t)i * 32 + fp] = pack_f16((a0 + b0) + (c0 + d0), (a1 + b1) + (c1 + d1));
}

// out[i,o] = a[i,:]@W[:,o] (+bias, relu if BR)
template <int FIN, int FOUT, bool BR>
__global__ void k_dense(const float* __restrict__ a, const float* __restrict__ W,
                        const float* __restrict__ b, float* __restrict__ out, int n) {
  __shared__ float sW[FIN * FOUT];
  __shared__ float sb[FOUT];
  for (int t = threadIdx.x; t < FIN * FOUT; t += blockDim.x) sW[t] = W[t];
  if (BR)
    for (int t = threadIdx.x; t < FOUT; t += blockDim.x) sb[t] = b[t];
  __syncthreads();
  int idx = blockIdx.x * blockDim.x + threadIdx.x;
  int i = idx / FOUT, o = idx % FOUT;
  if (i >= n) return;
  float acc = BR ? sb[o] : 0.f;
#pragma unroll
  for (int k = 0; k < FIN; ++k) acc += a[(size_t)i * FIN + k] * sW[k * FOUT + o];
  out[idx] = BR ? fmaxf(acc, 0.0f) : acc;
}

// dense 16->64 with bias+relu, fp16-packed output (2 outputs/thread)
__global__ void k_dense2_b(const float* __restrict__ a, const float* __restrict__ W,
                           const float* __restrict__ b, unsigned int* __restrict__ out,
                           int n) {
  __shared__ float sW[16 * 64];
  __shared__ float sb[64];
  for (int t = threadIdx.x; t < 16 * 64; t += blockDim.x) sW[t] = W[t];
  for (int t = threadIdx.x; t < 64; t += blockDim.x) sb[t] = b[t];
  __syncthreads();
  int idx = blockIdx.x * blockDim.x + threadIdx.x;
  int i = idx >> 5, op = idx & 31;
  if (i >= n) return;
  float acc0 = sb[2 * op], acc1 = sb[2 * op + 1];
#pragma unroll
  for (int k = 0; k < 16; ++k) {
    float av = a[(size_t)i * 16 + k];
    acc0 += av * sW[k * 64 + 2 * op];
    acc1 += av * sW[k * 64 + 2 * op + 1];
  }
  out[(size_t)i * 32 + op] = pack_f16(fmaxf(acc0, 0.f), fmaxf(acc1, 0.f));
}

// fused dense3(64->128)+relu+segmented mean-pool; NO LDS; fp16 input rows.
#define P4_NPW 16
__global__ __launch_bounds__(256) void k_dense3_pool4(
    const unsigned int* __restrict__ t3h, const float* __restrict__ W3,
    const float* __restrict__ b3, const int* __restrict__ batch,
    float* __restrict__ gsum) {
  int wu = blockIdx.x * 4 + (threadIdx.x >> 6);
  int lane = threadIdx.x & 63;
  int run = wu >> 1;
  int o = (wu & 1) * 64 + lane;
  int n0 = run * P4_NPW;
  if (n0 >= NN) return;
  float wcol[64];
#pragma unroll
  for (int k = 0; k < 64; ++k) wcol[k] = W3[k * 128 + o];
  float bias = b3[o];
  float acc = 0.f;
  int curg = -1;
#pragma unroll 1
  for (int j = 0; j < P4_NPW; ++j) {
    int n = n0 + j;
    if (n >= NN) break;
    int nu = __builtin_amdgcn_readfirstlane(n);
    const uint4* row = (const uint4*)(t3h + (size_t)nu * 32);
    float v = bias;
#pragma unroll
    for (int q = 0; q < 8; ++q) {
      uint4 r = row[q];
      float2 p0 = unpack_f16(r.x), p1 = unpack_f16(r.y);
      float2 p2 = unpack_f16(r.z), p3 = unpack_f16(r.w);
      v += p0.x * wcol[8 * q] + p0.y * wcol[8 * q + 1] + p1.x * wcol[8 * q + 2] +
           p1.y * wcol[8 * q + 3] + p2.x * wcol[8 * q + 4] + p2.y * wcol[8 * q + 5] +
           p3.x * wcol[8 * q + 6] + p3.y * wcol[8 * q + 7];
    }
    int g = batch[nu];
    if (g != curg) {
      if (curg >= 0) atomicAdd(&gsum[curg * 128 + o], acc);
      curg = g;
      acc = 0.f;
    }
    acc += fmaxf(v, 0.f);
  }
  if (curg >= 0) atomicAdd(&gsum[curg * 128 + o], acc);
}

// one wave per graph: logits = (gsum/cnt) @ Wl + bl; log_softmax over 16 classes
__global__ void k_head(const float* __restrict__ gsum, const int* __restrict__ gstart,
                       const float* __restrict__ Wl, const float* __restrict__ bl,
                       float* __restrict__ out) {
  int wave = threadIdx.x >> 6, lane = threadIdx.x & 63;
  int g = blockIdx.x * 4 + wave;
  if (g >= NG) return;
  int c = lane & 15, part = lane >> 4;
  float acc = 0.f;
#pragma unroll
  for (int kk = 0; kk < 32; ++kk) {
    int k = part * 32 + kk;
    acc += gsum[g * 128 + k] * Wl[k * NC + c];
  }
  acc += __shfl_xor(acc, 16);
  acc += __shfl_xor(acc, 32);
  int cnt = gstart[g + 1] - gstart[g];
  float inv = 1.0f / (float)max(cnt, 1);
  float logit = acc * inv + bl[c];
  float m = logit;
#pragma unroll
  for (int d = 1; d < 16; d <<= 1) m = fmaxf(m, __shfl_xor(m, d));
  float ex = expf(logit - m), s = ex;
#pragma unroll
  for (int d = 1; d < 16; d <<= 1) s += __shfl_xor(s, d);
  if (lane < 16) out[g * NC + lane] = logit - m - logf(s);
}

extern "C" void kernel_launch(void* const* d_in, const int* in_sizes, int n_in,
                              void* d_out, int out_size, void* d_ws, size_t ws_size,
                              hipStream_t stream) {
  const float* x = (const float*)d_in[0];
  const int* ei = (const int*)d_in[1];
  const int* batch = (const int*)d_in[2];
  const float* W1 = (const float*)d_in[3];
  const float* b1 = (const float*)d_in[4];
  const float* W2 = (const float*)d_in[5];
  const float* b2 = (const float*)d_in[6];
  const float* W3 = (const float*)d_in[7];
  const float* b3 = (const float*)d_in[8];
  const float* Wl = (const float*)d_in[9];
  const float* bl = (const float*)d_in[10];
  const int* src = ei;
  const int* dst = ei + NE;

  // workspace layout (~53 MB)
  int* bcnt = (int*)d_ws;                        // NBUK*NB1 = 76636 (scanned in place)
  int* bsum = bcnt + NBUK * NB1;                 // 1024
  int* bpref = bsum + 1024;                      // 1024
  int* gstart = bpref + 1024;                    // NG+2
  int* count = gstart + NG + 2;                  // NN
  int* offs = count + NN;                        // NN
  float* dinv = (float*)(offs + NN);             // NN
  float* gsum = (float*)(dinv + NN);             // NG*128
  unsigned int* packed = (unsigned int*)(gsum + NG * 128);  // NE
  int* csr = (int*)(packed + NE);                // NE (src only, 4B)
  float* t1 = (float*)(csr + NE);                // NN*16
  float* h1 = t1 + (size_t)NN * 16;              // NN*16
  unsigned int* h2b = (unsigned int*)(h1 + (size_t)NN * 16);  // NN*32 (fp16x2)
  unsigned int* t3h = h2b + (size_t)NN * 32;     // NN*32 (fp16x2)

  const int B = 256;
  const int NSC = NBUK * NB1;  // 76636

  // CSR build: two-level bucket sort, LDS atomics only
  k_zero_i<<<cdiv(NG * 128, B), B, 0, stream>>>((int*)gsum, NG * 128);
  k_p1a<<<NB1, 256, 0, stream>>>(dst, bcnt);
  k_bounds<<<cdiv(NN + 1, B), B, 0, stream>>>(batch, gstart);
  k_scan1<<<cdiv(NSC, 256), 256, 0, stream>>>(bcnt, bcnt, bsum, NSC);
  k_scan2<<<1, 512, 0, stream>>>(bsum, bpref, cdiv(NSC, 256));
  k_scan3b<<<cdiv(NSC, B), B, 0, stream>>>(bcnt, bpref, NSC);
  k_p1b<<<NB1, 256, 0, stream>>>(src, dst, bcnt, packed);
  k_p2<<<NBUK, 256, 0, stream>>>(packed, bcnt, count, offs, dinv, csr);

  // layer 1 (transform-first): t1 = x@W1; h1 = relu(agg(t1)+b1)
  k_dense<13, 16, false><<<cdiv((long long)NN * 16, B), B, 0, stream>>>(x, W1, b1, t1, NN);
  k_agg<16, 16, true><<<cdiv(NN, 16), B, 0, stream>>>(t1, csr, offs, count, dinv, b1, h1);
  // layer 2: t2 = agg(h1) (reuse t1); h2 = fp16(relu(t2@W2+b2))
  k_agg<16, 16, false><<<cdiv(NN, 16), B, 0, stream>>>(h1, csr, offs, count, dinv, nullptr, t1);
  k_dense2_b<<<cdiv((long long)NN * 32, B), B, 0, stream>>>(t1, W2, b2, h2b, NN);
  // layer 3: t3h = agg_fp16(h2); fused dense(64->128)+relu+pool
  k_agg_b64<<<cdiv(NN, 8), B, 0, stream>>>(h2b, csr, offs, count, dinv, t3h);
  {
    int runs = cdiv(NN, P4_NPW);
    k_dense3_pool4<<<cdiv(runs * 2, 4), 256, 0, stream>>>(t3h, W3, b3, batch, gsum);
  }

  // head
  k_head<<<NG / 4, B, 0, stream>>>(gsum, gstart, Wl, bl, (float*)d_out);
}

// Round 12
// 251.890 us; speedup vs baseline: 1.3116x; 1.0043x over previous
//
#include <hip/hip_runtime.h>
#include <hip/hip_fp16.h>

#define NN 100000
#define NE 1600000
#define NG 512
#define NC 16
#define NBUK 391  // coarse buckets = cdiv(NN,256), bucket = dst>>8
#define EPB 8192  // edges per phase-1 block
#define NB1 196   // cdiv(NE, EPB)

static inline int cdiv(long long a, int b) { return (int)((a + b - 1) / b); }

__device__ __forceinline__ unsigned int pack_f16(float x, float y) {
  __half2 h = __floats2half2_rn(x, y);
  return *reinterpret_cast<unsigned int*>(&h);
}
__device__ __forceinline__ float2 unpack_f16(unsigned int u) {
  __half2 h = *reinterpret_cast<__half2*>(&u);
  return __half22float2(h);
}

__global__ void k_zero_i(int* p, int n) {
  int i = blockIdx.x * blockDim.x + threadIdx.x;
  if (i < n) p[i] = 0;
}

// p1a: per-block coarse histogram (dst>>8) -> bcnt[bucket*NB1 + blk]  (LDS atomics only)
__global__ void k_p1a(const int* __restrict__ dst, int* __restrict__ bcnt) {
  __shared__ int sh[NBUK];
  int t = threadIdx.x, blk = blockIdx.x;
  for (int u = t; u < NBUK; u += 256) sh[u] = 0;
  __syncthreads();
  int e0 = blk * EPB;
#pragma unroll
  for (int k = 0; k < EPB / 256; ++k) {
    int e = e0 + k * 256 + t;
    if (e < NE) atomicAdd(&sh[dst[e] >> 8], 1);
  }
  __syncthreads();
  for (int u = t; u < NBUK; u += 256) bcnt[u * NB1 + blk] = sh[u];
}

// p1b: scatter edges into coarse-bucket partitions; packed = (dst&255)<<24 | src
__global__ void k_p1b(const int* __restrict__ src, const int* __restrict__ dst,
                      const int* __restrict__ bpos, unsigned int* __restrict__ packed) {
  __shared__ int sbase[NBUK];
  int t = threadIdx.x, blk = blockIdx.x;
  for (int u = t; u < NBUK; u += 256) sbase[u] = bpos[u * NB1 + blk];
  __syncthreads();
  int e0 = blk * EPB;
#pragma unroll
  for (int k = 0; k < EPB / 256; ++k) {
    int e = e0 + k * 256 + t;
    if (e < NE) {
      int d = dst[e];
      int pos = atomicAdd(&sbase[d >> 8], 1);  // LDS returning atomic
      packed[pos] = ((unsigned int)(d & 255) << 24) | (unsigned int)src[e];
    }
  }
}

// p2: per-bucket fine counting sort by dst-low8; emits count/offs/dinv + src-only csr
__global__ void k_p2(const unsigned int* __restrict__ packed, const int* __restrict__ bpos,
                     int* __restrict__ count, int* __restrict__ offs,
                     float* __restrict__ dinv, int* __restrict__ csr) {
  __shared__ int sh[256], sc[256], cur[256];
  int t = threadIdx.x, u = blockIdx.x;
  int s0 = bpos[u * NB1];
  int s1 = (u + 1 < NBUK) ? bpos[(u + 1) * NB1] : NE;
  sh[t] = 0;
  __syncthreads();
  for (int e = s0 + t; e < s1; e += 256) atomicAdd(&sh[packed[e] >> 24], 1);
  __syncthreads();
  sc[t] = sh[t];
  __syncthreads();
  for (int d = 1; d < 256; d <<= 1) {
    int a = (t >= d) ? sc[t - d] : 0;
    __syncthreads();
    sc[t] += a;
    __syncthreads();
  }
  int excl = sc[t] - sh[t];
  int node = u * 256 + t;
  if (node < NN) {
    count[node] = sh[t];
    offs[node] = s0 + excl;
    dinv[node] = rsqrtf((float)(sh[t] + 1));  // +1 self loop
  }
  cur[t] = s0 + excl;
  __syncthreads();
  for (int e = s0 + t; e < s1; e += 256) {
    unsigned int p = packed[e];
    int pos = atomicAdd(&cur[p >> 24], 1);  // LDS returning atomic
    csr[pos] = (int)(p & 0x00FFFFFFu);
  }
}

// graph boundaries from sorted batch
__global__ void k_bounds(const int* __restrict__ batch, int* __restrict__ gstart) {
  int i = blockIdx.x * blockDim.x + threadIdx.x;
  if (i > NN) return;
  int b = (i < NN) ? batch[i] : NG;
  int bp = (i > 0) ? batch[i - 1] : -1;
  for (int g = bp + 1; g <= b; ++g) gstart[g] = i;
}

// exclusive scan, 256/block; bsum gets block totals
__global__ void k_scan1(const int* __restrict__ in, int* __restrict__ out,
                        int* __restrict__ bsum, int n) {
  __shared__ int s[256];
  int t = threadIdx.x, i = blockIdx.x * 256 + t;
  int v = (i < n) ? in[i] : 0;
  s[t] = v;
  __syncthreads();
  for (int d = 1; d < 256; d <<= 1) {
    int a = (t >= d) ? s[t - d] : 0;
    __syncthreads();
    s[t] += a;
    __syncthreads();
  }
  if (i < n) out[i] = s[t] - v;  // exclusive
  if (t == 255) bsum[blockIdx.x] = s[255];
}

// single-block exclusive scan over <=512 values
__global__ void k_scan2(const int* __restrict__ in, int* __restrict__ out, int nb) {
  __shared__ int s[512];
  int t = threadIdx.x;
  int v = (t < nb) ? in[t] : 0;
  s[t] = v;
  __syncthreads();
  for (int d = 1; d < 512; d <<= 1) {
    int a = (t >= d) ? s[t - d] : 0;
    __syncthreads();
    s[t] += a;
    __syncthreads();
  }
  if (t < nb) out[t] = s[t] - v;
}

__global__ void k_scan3b(int* __restrict__ a, const int* __restrict__ bpref, int n) {
  int i = blockIdx.x * blockDim.x + threadIdx.x;
  if (i < n) a[i] += bpref[i >> 8];
}

// gather-reduce: pure unweighted sum of prescaled rows; epilogue v = acc*di (+bias,relu)
// PSOUT: multiply output by di again (prescale for next layer's agg)
template <int F, int LPN, bool BR, bool PSOUT>
__global__ void k_agg(const float* __restrict__ h, const int* __restrict__ csr,
                      const int* __restrict__ offs, const int* __restrict__ count,
                      const float* __restrict__ dinv, const float* __restrict__ bias,
                      float* __restrict__ out) {
  int wave = threadIdx.x >> 6, lane = threadIdx.x & 63;
  const int NPW = 64 / LPN;  // nodes per wave
  int i = (blockIdx.x * 4 + wave) * NPW + ((LPN == 64) ? 0 : (lane >> 4));
  int f = lane & (LPN - 1);
  if (i >= NN) return;
  int off = offs[i], cnt = count[i];
  float di = dinv[i];
  float a0 = 0.f, a1 = 0.f, a2 = 0.f, a3 = 0.f;
  float a4 = 0.f, a5 = 0.f, a6 = 0.f, a7 = 0.f;
  int j = 0;
  for (; j + 7 < cnt; j += 8) {
    int s0 = csr[off + j], s1 = csr[off + j + 1];
    int s2 = csr[off + j + 2], s3 = csr[off + j + 3];
    int s4 = csr[off + j + 4], s5 = csr[off + j + 5];
    int s6 = csr[off + j + 6], s7 = csr[off + j + 7];
    a0 += h[(size_t)s0 * F + f];
    a1 += h[(size_t)s1 * F + f];
    a2 += h[(size_t)s2 * F + f];
    a3 += h[(size_t)s3 * F + f];
    a4 += h[(size_t)s4 * F + f];
    a5 += h[(size_t)s5 * F + f];
    a6 += h[(size_t)s6 * F + f];
    a7 += h[(size_t)s7 * F + f];
  }
  for (; j < cnt; ++j) a0 += h[(size_t)csr[off + j] * F + f];
  a0 += h[(size_t)i * F + f];  // self loop (prescaled row)
  float v = ((a0 + a1) + (a2 + a3)) + ((a4 + a5) + (a6 + a7));
  v *= di;
  if (BR) v = fmaxf(v + bias[f], 0.f);
  if (PSOUT) v *= di;
  out[(size_t)i * F + f] = v;
}

// fp16 gather-reduce F=64: 32 lanes/node, 2 packed feats/lane; pure sum; out fp16 t3
__global__ void k_agg_b64(const unsigned int* __restrict__ h, const int* __restrict__ csr,
                          const int* __restrict__ offs, const int* __restrict__ count,
                          const float* __restrict__ dinv, unsigned int* __restrict__ out) {
  int wave = threadIdx.x >> 6, lane = threadIdx.x & 63;
  int i = (blockIdx.x * 4 + wave) * 2 + (lane >> 5);
  int fp = lane & 31;  // feature pair
  if (i >= NN) return;
  int off = offs[i], cnt = count[i];
  float di = dinv[i];
  float a0 = 0.f, a1 = 0.f, b0 = 0.f, b1 = 0.f;
  float c0 = 0.f, c1 = 0.f, d0 = 0.f, d1 = 0.f;
  int j = 0;
  for (; j + 7 < cnt; j += 8) {
    int s0 = csr[off + j], s1 = csr[off + j + 1];
    int s2 = csr[off + j + 2], s3 = csr[off + j + 3];
    int s4 = csr[off + j + 4], s5 = csr[off + j + 5];
    int s6 = csr[off + j + 6], s7 = csr[off + j + 7];
    unsigned int u0 = h[(size_t)s0 * 32 + fp];
    unsigned int u1 = h[(size_t)s1 * 32 + fp];
    unsigned int u2 = h[(size_t)s2 * 32 + fp];
    unsigned int u3 = h[(size_t)s3 * 32 + fp];
    unsigned int u4 = h[(size_t)s4 * 32 + fp];
    unsigned int u5 = h[(size_t)s5 * 32 + fp];
    unsigned int u6 = h[(size_t)s6 * 32 + fp];
    unsigned int u7 = h[(size_t)s7 * 32 + fp];
    float2 f0 = unpack_f16(u0), f1 = unpack_f16(u1);
    float2 f2 = unpack_f16(u2), f3 = unpack_f16(u3);
    float2 f4 = unpack_f16(u4), f5 = unpack_f16(u5);
    float2 f6 = unpack_f16(u6), f7 = unpack_f16(u7);
    a0 += f0.x; a1 += f0.y; b0 += f1.x; b1 += f1.y;
    c0 += f2.x; c1 += f2.y; d0 += f3.x; d1 += f3.y;
    a0 += f4.x; a1 += f4.y; b0 += f5.x; b1 += f5.y;
    c0 += f6.x; c1 += f6.y; d0 += f7.x; d1 += f7.y;
  }
  for (; j < cnt; ++j) {
    float2 f0 = unpack_f16(h[(size_t)csr[off + j] * 32 + fp]);
    a0 += f0.x; a1 += f0.y;
  }
  float2 fs = unpack_f16(h[(size_t)i * 32 + fp]);  // self loop (prescaled)
  a0 += fs.x; a1 += fs.y;
  float v0 = ((a0 + b0) + (c0 + d0)) * di;
  float v1 = ((a1 + b1) + (c1 + d1)) * di;
  out[(size_t)i * 32 + fp] = pack_f16(v0, v1);
}

// out[i,o] = a[i,:]@W[:,o] (+bias,relu if BR); PS: multiply by dinv[i] (prescale)
template <int FIN, int FOUT, bool BR, bool PS>
__global__ void k_dense(const float* __restrict__ a, const float* __restrict__ W,
                        const float* __restrict__ b, const float* __restrict__ dinv,
                        float* __restrict__ out, int n) {
  __shared__ float sW[FIN * FOUT];
  __shared__ float sb[FOUT];
  for (int t = threadIdx.x; t < FIN * FOUT; t += blockDim.x) sW[t] = W[t];
  if (BR)
    for (int t = threadIdx.x; t < FOUT; t += blockDim.x) sb[t] = b[t];
  __syncthreads();
  int idx = blockIdx.x * blockDim.x + threadIdx.x;
  int i = idx / FOUT, o = idx % FOUT;
  if (i >= n) return;
  float acc = BR ? sb[o] : 0.f;
#pragma unroll
  for (int k = 0; k < FIN; ++k) acc += a[(size_t)i * FIN + k] * sW[k * FOUT + o];
  if (BR) acc = fmaxf(acc, 0.0f);
  if (PS) acc *= dinv[i];
  out[idx] = acc;
}

// dense 16->64 with bias+relu, output prescaled by dinv and fp16-packed
__global__ void k_dense2_b(const float* __restrict__ a, const float* __restrict__ W,
                           const float* __restrict__ b, const float* __restrict__ dinv,
                           unsigned int* __restrict__ out, int n) {
  __shared__ float sW[16 * 64];
  __shared__ float sb[64];
  for (int t = threadIdx.x; t < 16 * 64; t += blockDim.x) sW[t] = W[t];
  for (int t = threadIdx.x; t < 64; t += blockDim.x) sb[t] = b[t];
  __syncthreads();
  int idx = blockIdx.x * blockDim.x + threadIdx.x;
  int i = idx >> 5, op = idx & 31;
  if (i >= n) return;
  float acc0 = sb[2 * op], acc1 = sb[2 * op + 1];
#pragma unroll
  for (int k = 0; k < 16; ++k) {
    float av = a[(size_t)i * 16 + k];
    acc0 += av * sW[k * 64 + 2 * op];
    acc1 += av * sW[k * 64 + 2 * op + 1];
  }
  float di = dinv[i];
  out[(size_t)i * 32 + op] = pack_f16(fmaxf(acc0, 0.f) * di, fmaxf(acc1, 0.f) * di);
}

// fused dense3(64->128)+relu+segmented mean-pool; NO LDS; fp16 input rows.
#define P4_NPW 16
__global__ __launch_bounds__(256) void k_dense3_pool4(
    const unsigned int* __restrict__ t3h, const float* __restrict__ W3,
    const float* __restrict__ b3, const int* __restrict__ batch,
    float* __restrict__ gsum) {
  int wu = blockIdx.x * 4 + (threadIdx.x >> 6);
  int lane = threadIdx.x & 63;
  int run = wu >> 1;
  int o = (wu & 1) * 64 + lane;
  int n0 = run * P4_NPW;
  if (n0 >= NN) return;
  float wcol[64];
#pragma unroll
  for (int k = 0; k < 64; ++k) wcol[k] = W3[k * 128 + o];
  float bias = b3[o];
  float acc = 0.f;
  int curg = -1;
#pragma unroll 1
  for (int j = 0; j < P4_NPW; ++j) {
    int n = n0 + j;
    if (n >= NN) break;
    int nu = __builtin_amdgcn_readfirstlane(n);
    const uint4* row = (const uint4*)(t3h + (size_t)nu * 32);
    float v = bias;
#pragma unroll
    for (int q = 0; q < 8; ++q) {
      uint4 r = row[q];
      float2 p0 = unpack_f16(r.x), p1 = unpack_f16(r.y);
      float2 p2 = unpack_f16(r.z), p3 = unpack_f16(r.w);
      v += p0.x * wcol[8 * q] + p0.y * wcol[8 * q + 1] + p1.x * wcol[8 * q + 2] +
           p1.y * wcol[8 * q + 3] + p2.x * wcol[8 * q + 4] + p2.y * wcol[8 * q + 5] +
           p3.x * wcol[8 * q + 6] + p3.y * wcol[8 * q + 7];
    }
    int g = batch[nu];
    if (g != curg) {
      if (curg >= 0) atomicAdd(&gsum[curg * 128 + o], acc);
      curg = g;
      acc = 0.f;
    }
    acc += fmaxf(v, 0.f);
  }
  if (curg >= 0) atomicAdd(&gsum[curg * 128 + o], acc);
}

// one wave per graph: logits = (gsum/cnt) @ Wl + bl; log_softmax over 16 classes
__global__ void k_head(const float* __restrict__ gsum, const int* __restrict__ gstart,
                       const float* __restrict__ Wl, const float* __restrict__ bl,
                       float* __restrict__ out) {
  int wave = threadIdx.x >> 6, lane = threadIdx.x & 63;
  int g = blockIdx.x * 4 + wave;
  if (g >= NG) return;
  int c = lane & 15, part = lane >> 4;
  float acc = 0.f;
#pragma unroll
  for (int kk = 0; kk < 32; ++kk) {
    int k = part * 32 + kk;
    acc += gsum[g * 128 + k] * Wl[k * NC + c];
  }
  acc += __shfl_xor(acc, 16);
  acc += __shfl_xor(acc, 32);
  int cnt = gstart[g + 1] - gstart[g];
  float inv = 1.0f / (float)max(cnt, 1);
  float logit = acc * inv + bl[c];
  float m = logit;
#pragma unroll
  for (int d = 1; d < 16; d <<= 1) m = fmaxf(m, __shfl_xor(m, d));
  float ex = expf(logit - m), s = ex;
#pragma unroll
  for (int d = 1; d < 16; d <<= 1) s += __shfl_xor(s, d);
  if (lane < 16) out[g * NC + lane] = logit - m - logf(s);
}

extern "C" void kernel_launch(void* const* d_in, const int* in_sizes, int n_in,
                              void* d_out, int out_size, void* d_ws, size_t ws_size,
                              hipStream_t stream) {
  const float* x = (const float*)d_in[0];
  const int* ei = (const int*)d_in[1];
  const int* batch = (const int*)d_in[2];
  const float* W1 = (const float*)d_in[3];
  const float* b1 = (const float*)d_in[4];
  const float* W2 = (const float*)d_in[5];
  const float* b2 = (const float*)d_in[6];
  const float* W3 = (const float*)d_in[7];
  const float* b3 = (const float*)d_in[8];
  const float* Wl = (const float*)d_in[9];
  const float* bl = (const float*)d_in[10];
  const int* src = ei;
  const int* dst = ei + NE;

  // workspace layout (~53 MB)
  int* bcnt = (int*)d_ws;                        // NBUK*NB1 = 76636 (scanned in place)
  int* bsum = bcnt + NBUK * NB1;                 // 1024
  int* bpref = bsum + 1024;                      // 1024
  int* gstart = bpref + 1024;                    // NG+2
  int* count = gstart + NG + 2;                  // NN
  int* offs = count + NN;                        // NN
  float* dinv = (float*)(offs + NN);             // NN
  float* gsum = (float*)(dinv + NN);             // NG*128
  unsigned int* packed = (unsigned int*)(gsum + NG * 128);  // NE
  int* csr = (int*)(packed + NE);                // NE (src only, 4B)
  float* t1p = (float*)(csr + NE);               // NN*16 (prescaled; reused as t2)
  float* h1p = t1p + (size_t)NN * 16;            // NN*16 (prescaled)
  unsigned int* h2b = (unsigned int*)(h1p + (size_t)NN * 16);  // NN*32 (fp16x2, prescaled)
  unsigned int* t3h = h2b + (size_t)NN * 32;     // NN*32 (fp16x2)

  const int B = 256;
  const int NSC = NBUK * NB1;  // 76636

  // CSR build: two-level bucket sort, LDS atomics only
  k_zero_i<<<cdiv(NG * 128, B), B, 0, stream>>>((int*)gsum, NG * 128);
  k_p1a<<<NB1, 256, 0, stream>>>(dst, bcnt);
  k_bounds<<<cdiv(NN + 1, B), B, 0, stream>>>(batch, gstart);
  k_scan1<<<cdiv(NSC, 256), 256, 0, stream>>>(bcnt, bcnt, bsum, NSC);
  k_scan2<<<1, 512, 0, stream>>>(bsum, bpref, cdiv(NSC, 256));
  k_scan3b<<<cdiv(NSC, B), B, 0, stream>>>(bcnt, bpref, NSC);
  k_p1b<<<NB1, 256, 0, stream>>>(src, dst, bcnt, packed);
  k_p2<<<NBUK, 256, 0, stream>>>(packed, bcnt, count, offs, dinv, csr);

  // layer 1: t1p = (x@W1)*dinv; h1p = relu(sum*di + b1)*di
  k_dense<13, 16, false, true><<<cdiv((long long)NN * 16, B), B, 0, stream>>>(
      x, W1, b1, dinv, t1p, NN);
  k_agg<16, 16, true, true><<<cdiv(NN, 16), B, 0, stream>>>(
      t1p, csr, offs, count, dinv, b1, h1p);
  // layer 2: t2 = sum(h1p)*di (reuse t1p); h2b = fp16(relu(t2@W2+b2)*di)
  k_agg<16, 16, false, false><<<cdiv(NN, 16), B, 0, stream>>>(
      h1p, csr, offs, count, dinv, nullptr, t1p);
  k_dense2_b<<<cdiv((long long)NN * 32, B), B, 0, stream>>>(t1p, W2, b2, dinv, h2b, NN);
  // layer 3: t3h = fp16(sum(h2b)*di); fused dense(64->128)+relu+pool
  k_agg_b64<<<cdiv(NN, 8), B, 0, stream>>>(h2b, csr, offs, count, dinv, t3h);
  {
    int runs = cdiv(NN, P4_NPW);
    k_dense3_pool4<<<cdiv(runs * 2, 4), 256, 0, stream>>>(t3h, W3, b3, batch, gsum);
  }

  // head
  k_head<<<NG / 4, B, 0, stream>>>(gsum, gstart, Wl, bl, (float*)d_out);
}

// Round 13
// 239.308 us; speedup vs baseline: 1.3805x; 1.0526x over previous
//
#include <hip/hip_runtime.h>
#include <hip/hip_fp16.h>

#define NN 100000
#define NE 1600000
#define NG 512
#define NC 16
#define NBUK 391  // coarse buckets = cdiv(NN,256), bucket = dst>>8
#define EPB 8192  // edges per phase-1 block
#define NB1 196   // cdiv(NE, EPB)

static inline int cdiv(long long a, int b) { return (int)((a + b - 1) / b); }

__device__ __forceinline__ unsigned int pack_f16(float x, float y) {
  __half2 h = __floats2half2_rn(x, y);
  return *reinterpret_cast<unsigned int*>(&h);
}
__device__ __forceinline__ float2 unpack_f16(unsigned int u) {
  __half2 h = *reinterpret_cast<__half2*>(&u);
  return __half22float2(h);
}

__global__ void k_zero_i(int* p, int n) {
  int i = blockIdx.x * blockDim.x + threadIdx.x;
  if (i < n) p[i] = 0;
}

// p1a: per-block coarse histogram (dst>>8) -> bcnt[bucket*NB1 + blk]  (LDS atomics only)
__global__ void k_p1a(const int* __restrict__ dst, int* __restrict__ bcnt) {
  __shared__ int sh[NBUK];
  int t = threadIdx.x, blk = blockIdx.x;
  for (int u = t; u < NBUK; u += 256) sh[u] = 0;
  __syncthreads();
  int e0 = blk * EPB;
#pragma unroll
  for (int k = 0; k < EPB / 256; ++k) {
    int e = e0 + k * 256 + t;
    if (e < NE) atomicAdd(&sh[dst[e] >> 8], 1);
  }
  __syncthreads();
  for (int u = t; u < NBUK; u += 256) bcnt[u * NB1 + blk] = sh[u];
}

// p1b: scatter edges into coarse-bucket partitions; packed = (dst&255)<<24 | src
__global__ void k_p1b(const int* __restrict__ src, const int* __restrict__ dst,
                      const int* __restrict__ bpos, unsigned int* __restrict__ packed) {
  __shared__ int sbase[NBUK];
  int t = threadIdx.x, blk = blockIdx.x;
  for (int u = t; u < NBUK; u += 256) sbase[u] = bpos[u * NB1 + blk];
  __syncthreads();
  int e0 = blk * EPB;
#pragma unroll
  for (int k = 0; k < EPB / 256; ++k) {
    int e = e0 + k * 256 + t;
    if (e < NE) {
      int d = dst[e];
      int pos = atomicAdd(&sbase[d >> 8], 1);  // LDS returning atomic
      packed[pos] = ((unsigned int)(d & 255) << 24) | (unsigned int)src[e];
    }
  }
}

// p2: per-bucket fine counting sort by dst-low8; emits count/offs/dinv + src-only csr
__global__ void k_p2(const unsigned int* __restrict__ packed, const int* __restrict__ bpos,
                     int* __restrict__ count, int* __restrict__ offs,
                     float* __restrict__ dinv, int* __restrict__ csr) {
  __shared__ int sh[256], sc[256], cur[256];
  int t = threadIdx.x, u = blockIdx.x;
  int s0 = bpos[u * NB1];
  int s1 = (u + 1 < NBUK) ? bpos[(u + 1) * NB1] : NE;
  sh[t] = 0;
  __syncthreads();
  for (int e = s0 + t; e < s1; e += 256) atomicAdd(&sh[packed[e] >> 24], 1);
  __syncthreads();
  sc[t] = sh[t];
  __syncthreads();
  for (int d = 1; d < 256; d <<= 1) {
    int a = (t >= d) ? sc[t - d] : 0;
    __syncthreads();
    sc[t] += a;
    __syncthreads();
  }
  int excl = sc[t] - sh[t];
  int node = u * 256 + t;
  if (node < NN) {
    count[node] = sh[t];
    offs[node] = s0 + excl;
    dinv[node] = rsqrtf((float)(sh[t] + 1));  // +1 self loop
  }
  cur[t] = s0 + excl;
  __syncthreads();
  for (int e = s0 + t; e < s1; e += 256) {
    unsigned int p = packed[e];
    int pos = atomicAdd(&cur[p >> 24], 1);  // LDS returning atomic
    csr[pos] = (int)(p & 0x00FFFFFFu);
  }
}

// graph boundaries from sorted batch
__global__ void k_bounds(const int* __restrict__ batch, int* __restrict__ gstart) {
  int i = blockIdx.x * blockDim.x + threadIdx.x;
  if (i > NN) return;
  int b = (i < NN) ? batch[i] : NG;
  int bp = (i > 0) ? batch[i - 1] : -1;
  for (int g = bp + 1; g <= b; ++g) gstart[g] = i;
}

// exclusive scan, 256/block; bsum gets block totals
__global__ void k_scan1(const int* __restrict__ in, int* __restrict__ out,
                        int* __restrict__ bsum, int n) {
  __shared__ int s[256];
  int t = threadIdx.x, i = blockIdx.x * 256 + t;
  int v = (i < n) ? in[i] : 0;
  s[t] = v;
  __syncthreads();
  for (int d = 1; d < 256; d <<= 1) {
    int a = (t >= d) ? s[t - d] : 0;
    __syncthreads();
    s[t] += a;
    __syncthreads();
  }
  if (i < n) out[i] = s[t] - v;  // exclusive
  if (t == 255) bsum[blockIdx.x] = s[255];
}

// single-block exclusive scan over <=512 values
__global__ void k_scan2(const int* __restrict__ in, int* __restrict__ out, int nb) {
  __shared__ int s[512];
  int t = threadIdx.x;
  int v = (t < nb) ? in[t] : 0;
  s[t] = v;
  __syncthreads();
  for (int d = 1; d < 512; d <<= 1) {
    int a = (t >= d) ? s[t - d] : 0;
    __syncthreads();
    s[t] += a;
    __syncthreads();
  }
  if (t < nb) out[t] = s[t] - v;
}

__global__ void k_scan3b(int* __restrict__ a, const int* __restrict__ bpref, int n) {
  int i = blockIdx.x * blockDim.x + threadIdx.x;
  if (i < n) a[i] += bpref[i >> 8];
}

// float4 gather-reduce for F=16: 4 lanes/node, float4 per lane; pure sum of
// prescaled rows; epilogue v = acc*di (+bias,relu); PSOUT: extra *di
template <bool BR, bool PSOUT>
__global__ void k_agg4(const float* __restrict__ h, const int* __restrict__ csr,
                       const int* __restrict__ offs, const int* __restrict__ count,
                       const float* __restrict__ dinv, const float* __restrict__ bias,
                       float* __restrict__ out) {
  int wave = threadIdx.x >> 6, lane = threadIdx.x & 63;
  int i = (blockIdx.x * 4 + wave) * 16 + (lane >> 2);
  int f4 = lane & 3;  // float4 index within row
  if (i >= NN) return;
  int off = offs[i], cnt = count[i];
  float di = dinv[i];
  float4 a0 = make_float4(0.f, 0.f, 0.f, 0.f), a1 = a0, a2 = a0, a3 = a0;
  int j = 0;
  for (; j + 3 < cnt; j += 4) {
    int s0 = csr[off + j], s1 = csr[off + j + 1];
    int s2 = csr[off + j + 2], s3 = csr[off + j + 3];
    float4 r0 = ((const float4*)(h + (size_t)s0 * 16))[f4];
    float4 r1 = ((const float4*)(h + (size_t)s1 * 16))[f4];
    float4 r2 = ((const float4*)(h + (size_t)s2 * 16))[f4];
    float4 r3 = ((const float4*)(h + (size_t)s3 * 16))[f4];
    a0.x += r0.x; a0.y += r0.y; a0.z += r0.z; a0.w += r0.w;
    a1.x += r1.x; a1.y += r1.y; a1.z += r1.z; a1.w += r1.w;
    a2.x += r2.x; a2.y += r2.y; a2.z += r2.z; a2.w += r2.w;
    a3.x += r3.x; a3.y += r3.y; a3.z += r3.z; a3.w += r3.w;
  }
  for (; j < cnt; ++j) {
    float4 r0 = ((const float4*)(h + (size_t)csr[off + j] * 16))[f4];
    a0.x += r0.x; a0.y += r0.y; a0.z += r0.z; a0.w += r0.w;
  }
  float4 rs = ((const float4*)(h + (size_t)i * 16))[f4];  // self loop (prescaled)
  float4 v;
  v.x = ((a0.x + a1.x) + (a2.x + a3.x) + rs.x) * di;
  v.y = ((a0.y + a1.y) + (a2.y + a3.y) + rs.y) * di;
  v.z = ((a0.z + a1.z) + (a2.z + a3.z) + rs.z) * di;
  v.w = ((a0.w + a1.w) + (a2.w + a3.w) + rs.w) * di;
  if (BR) {
    float4 bb = ((const float4*)bias)[f4];
    v.x = fmaxf(v.x + bb.x, 0.f);
    v.y = fmaxf(v.y + bb.y, 0.f);
    v.z = fmaxf(v.z + bb.z, 0.f);
    v.w = fmaxf(v.w + bb.w, 0.f);
  }
  if (PSOUT) { v.x *= di; v.y *= di; v.z *= di; v.w *= di; }
  ((float4*)(out + (size_t)i * 16))[f4] = v;
}

// fp16 gather-reduce F=64, uint4 loads: 8 lanes/node, 8 fp16 feats/lane
__global__ void k_agg_b64v(const unsigned int* __restrict__ h, const int* __restrict__ csr,
                           const int* __restrict__ offs, const int* __restrict__ count,
                           const float* __restrict__ dinv, unsigned int* __restrict__ out) {
  int wave = threadIdx.x >> 6, lane = threadIdx.x & 63;
  int i = (blockIdx.x * 4 + wave) * 8 + (lane >> 3);
  int q = lane & 7;  // uint4 index within 32-uint row
  if (i >= NN) return;
  int off = offs[i], cnt = count[i];
  float di = dinv[i];
  float acc[8] = {0.f, 0.f, 0.f, 0.f, 0.f, 0.f, 0.f, 0.f};
  int j = 0;
  for (; j + 3 < cnt; j += 4) {
    int s0 = csr[off + j], s1 = csr[off + j + 1];
    int s2 = csr[off + j + 2], s3 = csr[off + j + 3];
    uint4 r0 = ((const uint4*)(h + (size_t)s0 * 32))[q];
    uint4 r1 = ((const uint4*)(h + (size_t)s1 * 32))[q];
    uint4 r2 = ((const uint4*)(h + (size_t)s2 * 32))[q];
    uint4 r3 = ((const uint4*)(h + (size_t)s3 * 32))[q];
#define ACC4(r)                                                              \
  {                                                                          \
    float2 p0 = unpack_f16(r.x), p1 = unpack_f16(r.y);                       \
    float2 p2 = unpack_f16(r.z), p3 = unpack_f16(r.w);                       \
    acc[0] += p0.x; acc[1] += p0.y; acc[2] += p1.x; acc[3] += p1.y;          \
    acc[4] += p2.x; acc[5] += p2.y; acc[6] += p3.x; acc[7] += p3.y;          \
  }
    ACC4(r0) ACC4(r1) ACC4(r2) ACC4(r3)
  }
  for (; j < cnt; ++j) {
    uint4 r0 = ((const uint4*)(h + (size_t)csr[off + j] * 32))[q];
    ACC4(r0)
  }
  uint4 rs = ((const uint4*)(h + (size_t)i * 32))[q];  // self loop (prescaled)
  ACC4(rs)
#undef ACC4
  uint4 o;
  o.x = pack_f16(acc[0] * di, acc[1] * di);
  o.y = pack_f16(acc[2] * di, acc[3] * di);
  o.z = pack_f16(acc[4] * di, acc[5] * di);
  o.w = pack_f16(acc[6] * di, acc[7] * di);
  ((uint4*)(out + (size_t)i * 32))[q] = o;
}

// out[i,o] = a[i,:]@W[:,o] (+bias,relu if BR); PS: multiply by dinv[i] (prescale)
template <int FIN, int FOUT, bool BR, bool PS>
__global__ void k_dense(const float* __restrict__ a, const float* __restrict__ W,
                        const float* __restrict__ b, const float* __restrict__ dinv,
                        float* __restrict__ out, int n) {
  __shared__ float sW[FIN * FOUT];
  __shared__ float sb[FOUT];
  for (int t = threadIdx.x; t < FIN * FOUT; t += blockDim.x) sW[t] = W[t];
  if (BR)
    for (int t = threadIdx.x; t < FOUT; t += blockDim.x) sb[t] = b[t];
  __syncthreads();
  int idx = blockIdx.x * blockDim.x + threadIdx.x;
  int i = idx / FOUT, o = idx % FOUT;
  if (i >= n) return;
  float acc = BR ? sb[o] : 0.f;
#pragma unroll
  for (int k = 0; k < FIN; ++k) acc += a[(size_t)i * FIN + k] * sW[k * FOUT + o];
  if (BR) acc = fmaxf(acc, 0.0f);
  if (PS) acc *= dinv[i];
  out[idx] = acc;
}

// dense 16->64 with bias+relu, output prescaled by dinv and fp16-packed
__global__ void k_dense2_b(const float* __restrict__ a, const float* __restrict__ W,
                           const float* __restrict__ b, const float* __restrict__ dinv,
                           unsigned int* __restrict__ out, int n) {
  __shared__ float sW[16 * 64];
  __shared__ float sb[64];
  for (int t = threadIdx.x; t < 16 * 64; t += blockDim.x) sW[t] = W[t];
  for (int t = threadIdx.x; t < 64; t += blockDim.x) sb[t] = b[t];
  __syncthreads();
  int idx = blockIdx.x * blockDim.x + threadIdx.x;
  int i = idx >> 5, op = idx & 31;
  if (i >= n) return;
  float acc0 = sb[2 * op], acc1 = sb[2 * op + 1];
#pragma unroll
  for (int k = 0; k < 16; ++k) {
    float av = a[(size_t)i * 16 + k];
    acc0 += av * sW[k * 64 + 2 * op];
    acc1 += av * sW[k * 64 + 2 * op + 1];
  }
  float di = dinv[i];
  out[(size_t)i * 32 + op] = pack_f16(fmaxf(acc0, 0.f) * di, fmaxf(acc1, 0.f) * di);
}

// fused dense3(64->128)+relu+segmented mean-pool; NO LDS; fp16 input rows.
#define P4_NPW 16
__global__ __launch_bounds__(256) void k_dense3_pool4(
    const unsigned int* __restrict__ t3h, const float* __restrict__ W3,
    const float* __restrict__ b3, const int* __restrict__ batch,
    float* __restrict__ gsum) {
  int wu = blockIdx.x * 4 + (threadIdx.x >> 6);
  int lane = threadIdx.x & 63;
  int run = wu >> 1;
  int o = (wu & 1) * 64 + lane;
  int n0 = run * P4_NPW;
  if (n0 >= NN) return;
  float wcol[64];
#pragma unroll
  for (int k = 0; k < 64; ++k) wcol[k] = W3[k * 128 + o];
  float bias = b3[o];
  float acc = 0.f;
  int curg = -1;
#pragma unroll 1
  for (int j = 0; j < P4_NPW; ++j) {
    int n = n0 + j;
    if (n >= NN) break;
    int nu = __builtin_amdgcn_readfirstlane(n);
    const uint4* row = (const uint4*)(t3h + (size_t)nu * 32);
    float v = bias;
#pragma unroll
    for (int q = 0; q < 8; ++q) {
      uint4 r = row[q];
      float2 p0 = unpack_f16(r.x), p1 = unpack_f16(r.y);
      float2 p2 = unpack_f16(r.z), p3 = unpack_f16(r.w);
      v += p0.x * wcol[8 * q] + p0.y * wcol[8 * q + 1] + p1.x * wcol[8 * q + 2] +
           p1.y * wcol[8 * q + 3] + p2.x * wcol[8 * q + 4] + p2.y * wcol[8 * q + 5] +
           p3.x * wcol[8 * q + 6] + p3.y * wcol[8 * q + 7];
    }
    int g = batch[nu];
    if (g != curg) {
      if (curg >= 0) atomicAdd(&gsum[curg * 128 + o], acc);
      curg = g;
      acc = 0.f;
    }
    acc += fmaxf(v, 0.f);
  }
  if (curg >= 0) atomicAdd(&gsum[curg * 128 + o], acc);
}

// one wave per graph: logits = (gsum/cnt) @ Wl + bl; log_softmax over 16 classes
__global__ void k_head(const float* __restrict__ gsum, const int* __restrict__ gstart,
                       const float* __restrict__ Wl, const float* __restrict__ bl,
                       float* __restrict__ out) {
  int wave = threadIdx.x >> 6, lane = threadIdx.x & 63;
  int g = blockIdx.x * 4 + wave;
  if (g >= NG) return;
  int c = lane & 15, part = lane >> 4;
  float acc = 0.f;
#pragma unroll
  for (int kk = 0; kk < 32; ++kk) {
    int k = part * 32 + kk;
    acc += gsum[g * 128 + k] * Wl[k * NC + c];
  }
  acc += __shfl_xor(acc, 16);
  acc += __shfl_xor(acc, 32);
  int cnt = gstart[g + 1] - gstart[g];
  float inv = 1.0f / (float)max(cnt, 1);
  float logit = acc * inv + bl[c];
  float m = logit;
#pragma unroll
  for (int d = 1; d < 16; d <<= 1) m = fmaxf(m, __shfl_xor(m, d));
  float ex = expf(logit - m), s = ex;
#pragma unroll
  for (int d = 1; d < 16; d <<= 1) s += __shfl_xor(s, d);
  if (lane < 16) out[g * NC + lane] = logit - m - logf(s);
}

extern "C" void kernel_launch(void* const* d_in, const int* in_sizes, int n_in,
                              void* d_out, int out_size, void* d_ws, size_t ws_size,
                              hipStream_t stream) {
  const float* x = (const float*)d_in[0];
  const int* ei = (const int*)d_in[1];
  const int* batch = (const int*)d_in[2];
  const float* W1 = (const float*)d_in[3];
  const float* b1 = (const float*)d_in[4];
  const float* W2 = (const float*)d_in[5];
  const float* b2 = (const float*)d_in[6];
  const float* W3 = (const float*)d_in[7];
  const float* b3 = (const float*)d_in[8];
  const float* Wl = (const float*)d_in[9];
  const float* bl = (const float*)d_in[10];
  const int* src = ei;
  const int* dst = ei + NE;

  // workspace layout (~53 MB)
  int* bcnt = (int*)d_ws;                        // NBUK*NB1 = 76636 (scanned in place)
  int* bsum = bcnt + NBUK * NB1;                 // 1024
  int* bpref = bsum + 1024;                      // 1024
  int* gstart = bpref + 1024;                    // NG+2
  int* count = gstart + NG + 2;                  // NN
  int* offs = count + NN;                        // NN
  float* dinv = (float*)(offs + NN);             // NN
  float* gsum = (float*)(dinv + NN);             // NG*128
  unsigned int* packed = (unsigned int*)(gsum + NG * 128);  // NE
  int* csr = (int*)(packed + NE);                // NE (src only, 4B)
  float* t1p = (float*)(csr + NE);               // NN*16 (prescaled; reused as t2)
  float* h1p = t1p + (size_t)NN * 16;            // NN*16 (prescaled)
  unsigned int* h2b = (unsigned int*)(h1p + (size_t)NN * 16);  // NN*32 (fp16x2, prescaled)
  unsigned int* t3h = h2b + (size_t)NN * 32;     // NN*32 (fp16x2)

  const int B = 256;
  const int NSC = NBUK * NB1;  // 76636

  // CSR build: two-level bucket sort, LDS atomics only
  k_zero_i<<<cdiv(NG * 128, B), B, 0, stream>>>((int*)gsum, NG * 128);
  k_p1a<<<NB1, 256, 0, stream>>>(dst, bcnt);
  k_bounds<<<cdiv(NN + 1, B), B, 0, stream>>>(batch, gstart);
  k_scan1<<<cdiv(NSC, 256), 256, 0, stream>>>(bcnt, bcnt, bsum, NSC);
  k_scan2<<<1, 512, 0, stream>>>(bsum, bpref, cdiv(NSC, 256));
  k_scan3b<<<cdiv(NSC, B), B, 0, stream>>>(bcnt, bpref, NSC);
  k_p1b<<<NB1, 256, 0, stream>>>(src, dst, bcnt, packed);
  k_p2<<<NBUK, 256, 0, stream>>>(packed, bcnt, count, offs, dinv, csr);

  // layer 1: t1p = (x@W1)*dinv; h1p = relu(sum*di + b1)*di
  k_dense<13, 16, false, true><<<cdiv((long long)NN * 16, B), B, 0, stream>>>(
      x, W1, b1, dinv, t1p, NN);
  k_agg4<true, true><<<cdiv(NN, 64), B, 0, stream>>>(
      t1p, csr, offs, count, dinv, b1, h1p);
  // layer 2: t2 = sum(h1p)*di (reuse t1p); h2b = fp16(relu(t2@W2+b2)*di)
  k_agg4<false, false><<<cdiv(NN, 64), B, 0, stream>>>(
      h1p, csr, offs, count, dinv, nullptr, t1p);
  k_dense2_b<<<cdiv((long long)NN * 32, B), B, 0, stream>>>(t1p, W2, b2, dinv, h2b, NN);
  // layer 3: t3h = fp16(sum(h2b)*di); fused dense(64->128)+relu+pool
  k_agg_b64v<<<cdiv(NN, 32), B, 0, stream>>>(h2b, csr, offs, count, dinv, t3h);
  {
    int runs = cdiv(NN, P4_NPW);
    k_dense3_pool4<<<cdiv(runs * 2, 4), 256, 0, stream>>>(t3h, W3, b3, batch, gsum);
  }

  // head
  k_head<<<NG / 4, B, 0, stream>>>(gsum, gstart, Wl, bl, (float*)d_out);
}

// Round 14
// 216.507 us; speedup vs baseline: 1.5259x; 1.1053x over previous
//
#include <hip/hip_runtime.h>
#include <hip/hip_fp16.h>

#define NN 100000
#define NE 1600000
#define NG 512
#define NC 16
#define NBUK 391  // coarse buckets = cdiv(NN,256), bucket = dst>>8
#define EPB 8192  // edges per phase-1 block
#define NB1 196   // cdiv(NE, EPB)

static inline int cdiv(long long a, int b) { return (int)((a + b - 1) / b); }

__device__ __forceinline__ unsigned int pack_f16(float x, float y) {
  __half2 h = __floats2half2_rn(x, y);
  return *reinterpret_cast<unsigned int*>(&h);
}
__device__ __forceinline__ float2 unpack_f16(unsigned int u) {
  __half2 h = *reinterpret_cast<__half2*>(&u);
  return __half22float2(h);
}
__device__ __forceinline__ void acc8(float* acc, uint4 r) {
  float2 p0 = unpack_f16(r.x), p1 = unpack_f16(r.y);
  float2 p2 = unpack_f16(r.z), p3 = unpack_f16(r.w);
  acc[0] += p0.x; acc[1] += p0.y; acc[2] += p1.x; acc[3] += p1.y;
  acc[4] += p2.x; acc[5] += p2.y; acc[6] += p3.x; acc[7] += p3.y;
}

__global__ void k_zero_i(int* p, int n) {
  int i = blockIdx.x * blockDim.x + threadIdx.x;
  if (i < n) p[i] = 0;
}

// p1a: per-block coarse histogram (dst>>8) -> bcnt[bucket*NB1 + blk]  (LDS atomics only)
__global__ void k_p1a(const int* __restrict__ dst, int* __restrict__ bcnt) {
  __shared__ int sh[NBUK];
  int t = threadIdx.x, blk = blockIdx.x;
  for (int u = t; u < NBUK; u += 256) sh[u] = 0;
  __syncthreads();
  int e0 = blk * EPB;
#pragma unroll
  for (int k = 0; k < EPB / 256; ++k) {
    int e = e0 + k * 256 + t;
    if (e < NE) atomicAdd(&sh[dst[e] >> 8], 1);
  }
  __syncthreads();
  for (int u = t; u < NBUK; u += 256) bcnt[u * NB1 + blk] = sh[u];
}

// p1b: scatter edges into coarse-bucket partitions; packed = (dst&255)<<24 | src
__global__ void k_p1b(const int* __restrict__ src, const int* __restrict__ dst,
                      const int* __restrict__ bpos, unsigned int* __restrict__ packed) {
  __shared__ int sbase[NBUK];
  int t = threadIdx.x, blk = blockIdx.x;
  for (int u = t; u < NBUK; u += 256) sbase[u] = bpos[u * NB1 + blk];
  __syncthreads();
  int e0 = blk * EPB;
#pragma unroll
  for (int k = 0; k < EPB / 256; ++k) {
    int e = e0 + k * 256 + t;
    if (e < NE) {
      int d = dst[e];
      int pos = atomicAdd(&sbase[d >> 8], 1);  // LDS returning atomic
      packed[pos] = ((unsigned int)(d & 255) << 24) | (unsigned int)src[e];
    }
  }
}

// p2: per-bucket fine counting sort by dst-low8; emits count/offs/dinv + src-only csr
__global__ void k_p2(const unsigned int* __restrict__ packed, const int* __restrict__ bpos,
                     int* __restrict__ count, int* __restrict__ offs,
                     float* __restrict__ dinv, int* __restrict__ csr) {
  __shared__ int sh[256], sc[256], cur[256];
  int t = threadIdx.x, u = blockIdx.x;
  int s0 = bpos[u * NB1];
  int s1 = (u + 1 < NBUK) ? bpos[(u + 1) * NB1] : NE;
  sh[t] = 0;
  __syncthreads();
  for (int e = s0 + t; e < s1; e += 256) atomicAdd(&sh[packed[e] >> 24], 1);
  __syncthreads();
  sc[t] = sh[t];
  __syncthreads();
  for (int d = 1; d < 256; d <<= 1) {
    int a = (t >= d) ? sc[t - d] : 0;
    __syncthreads();
    sc[t] += a;
    __syncthreads();
  }
  int excl = sc[t] - sh[t];
  int node = u * 256 + t;
  if (node < NN) {
    count[node] = sh[t];
    offs[node] = s0 + excl;
    dinv[node] = rsqrtf((float)(sh[t] + 1));  // +1 self loop
  }
  cur[t] = s0 + excl;
  __syncthreads();
  for (int e = s0 + t; e < s1; e += 256) {
    unsigned int p = packed[e];
    int pos = atomicAdd(&cur[p >> 24], 1);  // LDS returning atomic
    csr[pos] = (int)(p & 0x00FFFFFFu);
  }
}

// graph boundaries from sorted batch
__global__ void k_bounds(const int* __restrict__ batch, int* __restrict__ gstart) {
  int i = blockIdx.x * blockDim.x + threadIdx.x;
  if (i > NN) return;
  int b = (i < NN) ? batch[i] : NG;
  int bp = (i > 0) ? batch[i - 1] : -1;
  for (int g = bp + 1; g <= b; ++g) gstart[g] = i;
}

// exclusive scan, 256/block; bsum gets block totals
__global__ void k_scan1(const int* __restrict__ in, int* __restrict__ out,
                        int* __restrict__ bsum, int n) {
  __shared__ int s[256];
  int t = threadIdx.x, i = blockIdx.x * 256 + t;
  int v = (i < n) ? in[i] : 0;
  s[t] = v;
  __syncthreads();
  for (int d = 1; d < 256; d <<= 1) {
    int a = (t >= d) ? s[t - d] : 0;
    __syncthreads();
    s[t] += a;
    __syncthreads();
  }
  if (i < n) out[i] = s[t] - v;  // exclusive
  if (t == 255) bsum[blockIdx.x] = s[255];
}

// single-block exclusive scan over <=512 values
__global__ void k_scan2(const int* __restrict__ in, int* __restrict__ out, int nb) {
  __shared__ int s[512];
  int t = threadIdx.x;
  int v = (t < nb) ? in[t] : 0;
  s[t] = v;
  __syncthreads();
  for (int d = 1; d < 512; d <<= 1) {
    int a = (t >= d) ? s[t - d] : 0;
    __syncthreads();
    s[t] += a;
    __syncthreads();
  }
  if (t < nb) out[t] = s[t] - v;
}

__global__ void k_scan3b(int* __restrict__ a, const int* __restrict__ bpref, int n) {
  int i = blockIdx.x * blockDim.x + threadIdx.x;
  if (i < n) a[i] += bpref[i >> 8];
}

// fp16 gather-reduce for F=16 rows (32B): 2 lanes/node, uint4 per lane, unroll 8.
// Pure sum of prescaled rows; epilogue v=acc*di (+bias,relu); PSOUT: extra *di.
template <bool BR, bool PSOUT>
__global__ void k_agg16h(const unsigned int* __restrict__ h, const int* __restrict__ csr,
                         const int* __restrict__ offs, const int* __restrict__ count,
                         const float* __restrict__ dinv, const float* __restrict__ bias,
                         unsigned int* __restrict__ out) {
  int wave = threadIdx.x >> 6, lane = threadIdx.x & 63;
  int i = (blockIdx.x * 4 + wave) * 32 + (lane >> 1);
  int q = lane & 1;  // uint4 half of the 8-uint row
  if (i >= NN) return;
  int off = offs[i], cnt = count[i];
  float di = dinv[i];
  float acc[8] = {0.f, 0.f, 0.f, 0.f, 0.f, 0.f, 0.f, 0.f};
  int j = 0;
  for (; j + 7 < cnt; j += 8) {
    int s0 = csr[off + j], s1 = csr[off + j + 1];
    int s2 = csr[off + j + 2], s3 = csr[off + j + 3];
    int s4 = csr[off + j + 4], s5 = csr[off + j + 5];
    int s6 = csr[off + j + 6], s7 = csr[off + j + 7];
    uint4 r0 = ((const uint4*)(h + (size_t)s0 * 8))[q];
    uint4 r1 = ((const uint4*)(h + (size_t)s1 * 8))[q];
    uint4 r2 = ((const uint4*)(h + (size_t)s2 * 8))[q];
    uint4 r3 = ((const uint4*)(h + (size_t)s3 * 8))[q];
    uint4 r4 = ((const uint4*)(h + (size_t)s4 * 8))[q];
    uint4 r5 = ((const uint4*)(h + (size_t)s5 * 8))[q];
    uint4 r6 = ((const uint4*)(h + (size_t)s6 * 8))[q];
    uint4 r7 = ((const uint4*)(h + (size_t)s7 * 8))[q];
    acc8(acc, r0); acc8(acc, r1); acc8(acc, r2); acc8(acc, r3);
    acc8(acc, r4); acc8(acc, r5); acc8(acc, r6); acc8(acc, r7);
  }
  for (; j < cnt; ++j) {
    uint4 r0 = ((const uint4*)(h + (size_t)csr[off + j] * 8))[q];
    acc8(acc, r0);
  }
  uint4 rs = ((const uint4*)(h + (size_t)i * 8))[q];  // self loop (prescaled)
  acc8(acc, rs);
  float v[8];
#pragma unroll
  for (int t = 0; t < 8; ++t) {
    v[t] = acc[t] * di;
    if (BR) v[t] = fmaxf(v[t] + bias[q * 8 + t], 0.f);
    if (PSOUT) v[t] *= di;
  }
  uint4 o;
  o.x = pack_f16(v[0], v[1]);
  o.y = pack_f16(v[2], v[3]);
  o.z = pack_f16(v[4], v[5]);
  o.w = pack_f16(v[6], v[7]);
  ((uint4*)(out + (size_t)i * 8))[q] = o;
}

// fp16 gather-reduce F=64 (128B rows): 8 lanes/node, uint4 per lane, unroll 8
__global__ void k_agg_b64v(const unsigned int* __restrict__ h, const int* __restrict__ csr,
                           const int* __restrict__ offs, const int* __restrict__ count,
                           const float* __restrict__ dinv, unsigned int* __restrict__ out) {
  int wave = threadIdx.x >> 6, lane = threadIdx.x & 63;
  int i = (blockIdx.x * 4 + wave) * 8 + (lane >> 3);
  int q = lane & 7;  // uint4 index within 32-uint row
  if (i >= NN) return;
  int off = offs[i], cnt = count[i];
  float di = dinv[i];
  float acc[8] = {0.f, 0.f, 0.f, 0.f, 0.f, 0.f, 0.f, 0.f};
  int j = 0;
  for (; j + 7 < cnt; j += 8) {
    int s0 = csr[off + j], s1 = csr[off + j + 1];
    int s2 = csr[off + j + 2], s3 = csr[off + j + 3];
    int s4 = csr[off + j + 4], s5 = csr[off + j + 5];
    int s6 = csr[off + j + 6], s7 = csr[off + j + 7];
    uint4 r0 = ((const uint4*)(h + (size_t)s0 * 32))[q];
    uint4 r1 = ((const uint4*)(h + (size_t)s1 * 32))[q];
    uint4 r2 = ((const uint4*)(h + (size_t)s2 * 32))[q];
    uint4 r3 = ((const uint4*)(h + (size_t)s3 * 32))[q];
    uint4 r4 = ((const uint4*)(h + (size_t)s4 * 32))[q];
    uint4 r5 = ((const uint4*)(h + (size_t)s5 * 32))[q];
    uint4 r6 = ((const uint4*)(h + (size_t)s6 * 32))[q];
    uint4 r7 = ((const uint4*)(h + (size_t)s7 * 32))[q];
    acc8(acc, r0); acc8(acc, r1); acc8(acc, r2); acc8(acc, r3);
    acc8(acc, r4); acc8(acc, r5); acc8(acc, r6); acc8(acc, r7);
  }
  for (; j < cnt; ++j) {
    uint4 r0 = ((const uint4*)(h + (size_t)csr[off + j] * 32))[q];
    acc8(acc, r0);
  }
  uint4 rs = ((const uint4*)(h + (size_t)i * 32))[q];  // self loop (prescaled)
  acc8(acc, rs);
  uint4 o;
  o.x = pack_f16(acc[0] * di, acc[1] * di);
  o.y = pack_f16(acc[2] * di, acc[3] * di);
  o.z = pack_f16(acc[4] * di, acc[5] * di);
  o.w = pack_f16(acc[6] * di, acc[7] * di);
  ((uint4*)(out + (size_t)i * 32))[q] = o;
}

// dense1: t1p = fp16((x@W1)*dinv); thread computes 2 packed outputs
__global__ void k_dense1_h(const float* __restrict__ x, const float* __restrict__ W,
                           const float* __restrict__ dinv, unsigned int* __restrict__ out,
                           int n) {
  __shared__ float sW[13 * 16];
  for (int t = threadIdx.x; t < 13 * 16; t += blockDim.x) sW[t] = W[t];
  __syncthreads();
  int idx = blockIdx.x * blockDim.x + threadIdx.x;
  int i = idx >> 3, u = idx & 7;
  if (i >= n) return;
  float a0 = 0.f, a1 = 0.f;
#pragma unroll
  for (int k = 0; k < 13; ++k) {
    float av = x[(size_t)i * 13 + k];
    a0 += av * sW[k * 16 + 2 * u];
    a1 += av * sW[k * 16 + 2 * u + 1];
  }
  float di = dinv[i];
  out[(size_t)i * 8 + u] = pack_f16(a0 * di, a1 * di);
}

// dense2: h2b = fp16(relu(t2@W2+b2)*di); fp16-packed input rows (8 uints)
__global__ void k_dense2_h(const unsigned int* __restrict__ a, const float* __restrict__ W,
                           const float* __restrict__ b, const float* __restrict__ dinv,
                           unsigned int* __restrict__ out, int n) {
  __shared__ float sW[16 * 64];
  __shared__ float sb[64];
  for (int t = threadIdx.x; t < 16 * 64; t += blockDim.x) sW[t] = W[t];
  for (int t = threadIdx.x; t < 64; t += blockDim.x) sb[t] = b[t];
  __syncthreads();
  int idx = blockIdx.x * blockDim.x + threadIdx.x;
  int i = idx >> 5, op = idx & 31;
  if (i >= n) return;
  float av[16];
#pragma unroll
  for (int u = 0; u < 8; ++u) {
    float2 p = unpack_f16(a[(size_t)i * 8 + u]);
    av[2 * u] = p.x;
    av[2 * u + 1] = p.y;
  }
  float acc0 = sb[2 * op], acc1 = sb[2 * op + 1];
#pragma unroll
  for (int k = 0; k < 16; ++k) {
    acc0 += av[k] * sW[k * 64 + 2 * op];
    acc1 += av[k] * sW[k * 64 + 2 * op + 1];
  }
  float di = dinv[i];
  out[(size_t)i * 32 + op] = pack_f16(fmaxf(acc0, 0.f) * di, fmaxf(acc1, 0.f) * di);
}

// fused dense3(64->128)+relu+segmented mean-pool; NO LDS; fp16 input rows.
#define P4_NPW 16
__global__ __launch_bounds__(256) void k_dense3_pool4(
    const unsigned int* __restrict__ t3h, const float* __restrict__ W3,
    const float* __restrict__ b3, const int* __restrict__ batch,
    float* __restrict__ gsum) {
  int wu = blockIdx.x * 4 + (threadIdx.x >> 6);
  int lane = threadIdx.x & 63;
  int run = wu >> 1;
  int o = (wu & 1) * 64 + lane;
  int n0 = run * P4_NPW;
  if (n0 >= NN) return;
  float wcol[64];
#pragma unroll
  for (int k = 0; k < 64; ++k) wcol[k] = W3[k * 128 + o];
  float bias = b3[o];
  float acc = 0.f;
  int curg = -1;
#pragma unroll 1
  for (int j = 0; j < P4_NPW; ++j) {
    int n = n0 + j;
    if (n >= NN) break;
    int nu = __builtin_amdgcn_readfirstlane(n);
    const uint4* row = (const uint4*)(t3h + (size_t)nu * 32);
    float v = bias;
#pragma unroll
    for (int q = 0; q < 8; ++q) {
      uint4 r = row[q];
      float2 p0 = unpack_f16(r.x), p1 = unpack_f16(r.y);
      float2 p2 = unpack_f16(r.z), p3 = unpack_f16(r.w);
      v += p0.x * wcol[8 * q] + p0.y * wcol[8 * q + 1] + p1.x * wcol[8 * q + 2] +
           p1.y * wcol[8 * q + 3] + p2.x * wcol[8 * q + 4] + p2.y * wcol[8 * q + 5] +
           p3.x * wcol[8 * q + 6] + p3.y * wcol[8 * q + 7];
    }
    int g = batch[nu];
    if (g != curg) {
      if (curg >= 0) atomicAdd(&gsum[curg * 128 + o], acc);
      curg = g;
      acc = 0.f;
    }
    acc += fmaxf(v, 0.f);
  }
  if (curg >= 0) atomicAdd(&gsum[curg * 128 + o], acc);
}

// one wave per graph: logits = (gsum/cnt) @ Wl + bl; log_softmax over 16 classes
__global__ void k_head(const float* __restrict__ gsum, const int* __restrict__ gstart,
                       const float* __restrict__ Wl, const float* __restrict__ bl,
                       float* __restrict__ out) {
  int wave = threadIdx.x >> 6, lane = threadIdx.x & 63;
  int g = blockIdx.x * 4 + wave;
  if (g >= NG) return;
  int c = lane & 15, part = lane >> 4;
  float acc = 0.f;
#pragma unroll
  for (int kk = 0; kk < 32; ++kk) {
    int k = part * 32 + kk;
    acc += gsum[g * 128 + k] * Wl[k * NC + c];
  }
  acc += __shfl_xor(acc, 16);
  acc += __shfl_xor(acc, 32);
  int cnt = gstart[g + 1] - gstart[g];
  float inv = 1.0f / (float)max(cnt, 1);
  float logit = acc * inv + bl[c];
  float m = logit;
#pragma unroll
  for (int d = 1; d < 16; d <<= 1) m = fmaxf(m, __shfl_xor(m, d));
  float ex = expf(logit - m), s = ex;
#pragma unroll
  for (int d = 1; d < 16; d <<= 1) s += __shfl_xor(s, d);
  if (lane < 16) out[g * NC + lane] = logit - m - logf(s);
}

extern "C" void kernel_launch(void* const* d_in, const int* in_sizes, int n_in,
                              void* d_out, int out_size, void* d_ws, size_t ws_size,
                              hipStream_t stream) {
  const float* x = (const float*)d_in[0];
  const int* ei = (const int*)d_in[1];
  const int* batch = (const int*)d_in[2];
  const float* W1 = (const float*)d_in[3];
  const float* b1 = (const float*)d_in[4];
  const float* W2 = (const float*)d_in[5];
  const float* b2 = (const float*)d_in[6];
  const float* W3 = (const float*)d_in[7];
  const float* b3 = (const float*)d_in[8];
  const float* Wl = (const float*)d_in[9];
  const float* bl = (const float*)d_in[10];
  const int* src = ei;
  const int* dst = ei + NE;

  // workspace layout (~50 MB)
  int* bcnt = (int*)d_ws;                        // NBUK*NB1 = 76636 (scanned in place)
  int* bsum = bcnt + NBUK * NB1;                 // 1024
  int* bpref = bsum + 1024;                      // 1024
  int* gstart = bpref + 1024;                    // NG+2
  int* count = gstart + NG + 2;                  // NN
  int* offs = count + NN;                        // NN
  float* dinv = (float*)(offs + NN);             // NN
  float* gsum = (float*)(dinv + NN);             // NG*128
  unsigned int* packed = (unsigned int*)(gsum + NG * 128);  // NE
  int* csr = (int*)(packed + NE);                // NE (src only, 4B)
  unsigned int* t1p = (unsigned int*)(csr + NE); // NN*8 (fp16x2, prescaled)
  unsigned int* h1p = t1p + (size_t)NN * 8;      // NN*8 (fp16x2, prescaled)
  unsigned int* t2p = h1p + (size_t)NN * 8;      // NN*8 (fp16x2)
  unsigned int* h2b = t2p + (size_t)NN * 8;      // NN*32 (fp16x2, prescaled)
  unsigned int* t3h = h2b + (size_t)NN * 32;     // NN*32 (fp16x2)

  const int B = 256;
  const int NSC = NBUK * NB1;  // 76636

  // CSR build: two-level bucket sort, LDS atomics only
  k_zero_i<<<cdiv(NG * 128, B), B, 0, stream>>>((int*)gsum, NG * 128);
  k_p1a<<<NB1, 256, 0, stream>>>(dst, bcnt);
  k_bounds<<<cdiv(NN + 1, B), B, 0, stream>>>(batch, gstart);
  k_scan1<<<cdiv(NSC, 256), 256, 0, stream>>>(bcnt, bcnt, bsum, NSC);
  k_scan2<<<1, 512, 0, stream>>>(bsum, bpref, cdiv(NSC, 256));
  k_scan3b<<<cdiv(NSC, B), B, 0, stream>>>(bcnt, bpref, NSC);
  k_p1b<<<NB1, 256, 0, stream>>>(src, dst, bcnt, packed);
  k_p2<<<NBUK, 256, 0, stream>>>(packed, bcnt, count, offs, dinv, csr);

  // layer 1: t1p = fp16((x@W1)*di); h1p = fp16(relu(sum*di + b1)*di)
  k_dense1_h<<<cdiv((long long)NN * 8, B), B, 0, stream>>>(x, W1, dinv, t1p, NN);
  k_agg16h<true, true><<<cdiv(NN, 128), B, 0, stream>>>(
      t1p, csr, offs, count, dinv, b1, h1p);
  // layer 2: t2p = fp16(sum(h1p)*di); h2b = fp16(relu(t2@W2+b2)*di)
  k_agg16h<false, false><<<cdiv(NN, 128), B, 0, stream>>>(
      h1p, csr, offs, count, dinv, nullptr, t2p);
  k_dense2_h<<<cdiv((long long)NN * 32, B), B, 0, stream>>>(t2p, W2, b2, dinv, h2b, NN);
  // layer 3: t3h = fp16(sum(h2b)*di); fused dense(64->128)+relu+pool
  k_agg_b64v<<<cdiv(NN, 32), B, 0, stream>>>(h2b, csr, offs, count, dinv, t3h);
  {
    int runs = cdiv(NN, P4_NPW);
    k_dense3_pool4<<<cdiv(runs * 2, 4), 256, 0, stream>>>(t3h, W3, b3, batch, gsum);
  }

  // head
  k_head<<<NG / 4, B, 0, stream>>>(gsum, gstart, Wl, bl, (float*)d_out);
}

// Round 15
// 192.403 us; speedup vs baseline: 1.7171x; 1.1253x over previous
//
#include <hip/hip_runtime.h>
#include <hip/hip_fp16.h>

#define NN 100000
#define NE 1600000
#define NG 512
#define NC 16
#define NBUK 391  // coarse buckets = cdiv(NN,256), bucket = dst>>8
#define EPB 8192  // edges per phase-1 block
#define NB1 196   // cdiv(NE, EPB)

static inline int cdiv(long long a, int b) { return (int)((a + b - 1) / b); }

typedef __attribute__((ext_vector_type(2))) float floatx2;

__device__ __forceinline__ unsigned int pack_f16(float x, float y) {
  __half2 h = __floats2half2_rn(x, y);
  return *reinterpret_cast<unsigned int*>(&h);
}
__device__ __forceinline__ float2 unpack_f16(unsigned int u) {
  __half2 h = *reinterpret_cast<__half2*>(&u);
  return __half22float2(h);
}
__device__ __forceinline__ void acc8(float* acc, uint4 r) {
  float2 p0 = unpack_f16(r.x), p1 = unpack_f16(r.y);
  float2 p2 = unpack_f16(r.z), p3 = unpack_f16(r.w);
  acc[0] += p0.x; acc[1] += p0.y; acc[2] += p1.x; acc[3] += p1.y;
  acc[4] += p2.x; acc[5] += p2.y; acc[6] += p3.x; acc[7] += p3.y;
}
// decode 4 fp8 (e4m3) from one uint into acc[b..b+3]
__device__ __forceinline__ void accf8(float* acc, unsigned int u) {
  floatx2 lo = __builtin_amdgcn_cvt_pk_f32_fp8(u, false);
  floatx2 hi = __builtin_amdgcn_cvt_pk_f32_fp8(u, true);
  acc[0] += lo.x; acc[1] += lo.y; acc[2] += hi.x; acc[3] += hi.y;
}

__global__ void k_zero_i(int* p, int n) {
  int i = blockIdx.x * blockDim.x + threadIdx.x;
  if (i < n) p[i] = 0;
}

// p1a: per-block coarse histogram (dst>>8) -> bcnt[bucket*NB1 + blk]  (LDS atomics only)
__global__ void k_p1a(const int* __restrict__ dst, int* __restrict__ bcnt) {
  __shared__ int sh[NBUK];
  int t = threadIdx.x, blk = blockIdx.x;
  for (int u = t; u < NBUK; u += 256) sh[u] = 0;
  __syncthreads();
  int e0 = blk * EPB;
#pragma unroll
  for (int k = 0; k < EPB / 256; ++k) {
    int e = e0 + k * 256 + t;
    if (e < NE) atomicAdd(&sh[dst[e] >> 8], 1);
  }
  __syncthreads();
  for (int u = t; u < NBUK; u += 256) bcnt[u * NB1 + blk] = sh[u];
}

// p1b: scatter edges into coarse-bucket partitions; packed = (dst&255)<<24 | src
__global__ void k_p1b(const int* __restrict__ src, const int* __restrict__ dst,
                      const int* __restrict__ bpos, unsigned int* __restrict__ packed) {
  __shared__ int sbase[NBUK];
  int t = threadIdx.x, blk = blockIdx.x;
  for (int u = t; u < NBUK; u += 256) sbase[u] = bpos[u * NB1 + blk];
  __syncthreads();
  int e0 = blk * EPB;
#pragma unroll
  for (int k = 0; k < EPB / 256; ++k) {
    int e = e0 + k * 256 + t;
    if (e < NE) {
      int d = dst[e];
      int pos = atomicAdd(&sbase[d >> 8], 1);  // LDS returning atomic
      packed[pos] = ((unsigned int)(d & 255) << 24) | (unsigned int)src[e];
    }
  }
}

// p2: per-bucket fine counting sort by dst-low8; emits count/offs/dinv + src-only csr
__global__ void k_p2(const unsigned int* __restrict__ packed, const int* __restrict__ bpos,
                     int* __restrict__ count, int* __restrict__ offs,
                     float* __restrict__ dinv, int* __restrict__ csr) {
  __shared__ int sh[256], sc[256], cur[256];
  int t = threadIdx.x, u = blockIdx.x;
  int s0 = bpos[u * NB1];
  int s1 = (u + 1 < NBUK) ? bpos[(u + 1) * NB1] : NE;
  sh[t] = 0;
  __syncthreads();
  for (int e = s0 + t; e < s1; e += 256) atomicAdd(&sh[packed[e] >> 24], 1);
  __syncthreads();
  sc[t] = sh[t];
  __syncthreads();
  for (int d = 1; d < 256; d <<= 1) {
    int a = (t >= d) ? sc[t - d] : 0;
    __syncthreads();
    sc[t] += a;
    __syncthreads();
  }
  int excl = sc[t] - sh[t];
  int node = u * 256 + t;
  if (node < NN) {
    count[node] = sh[t];
    offs[node] = s0 + excl;
    dinv[node] = rsqrtf((float)(sh[t] + 1));  // +1 self loop
  }
  cur[t] = s0 + excl;
  __syncthreads();
  for (int e = s0 + t; e < s1; e += 256) {
    unsigned int p = packed[e];
    int pos = atomicAdd(&cur[p >> 24], 1);  // LDS returning atomic
    csr[pos] = (int)(p & 0x00FFFFFFu);
  }
}

// graph boundaries from sorted batch
__global__ void k_bounds(const int* __restrict__ batch, int* __restrict__ gstart) {
  int i = blockIdx.x * blockDim.x + threadIdx.x;
  if (i > NN) return;
  int b = (i < NN) ? batch[i] : NG;
  int bp = (i > 0) ? batch[i - 1] : -1;
  for (int g = bp + 1; g <= b; ++g) gstart[g] = i;
}

// exclusive scan, 256/block; bsum gets block totals
__global__ void k_scan1(const int* __restrict__ in, int* __restrict__ out,
                        int* __restrict__ bsum, int n) {
  __shared__ int s[256];
  int t = threadIdx.x, i = blockIdx.x * 256 + t;
  int v = (i < n) ? in[i] : 0;
  s[t] = v;
  __syncthreads();
  for (int d = 1; d < 256; d <<= 1) {
    int a = (t >= d) ? s[t - d] : 0;
    __syncthreads();
    s[t] += a;
    __syncthreads();
  }
  if (i < n) out[i] = s[t] - v;  // exclusive
  if (t == 255) bsum[blockIdx.x] = s[255];
}

// single-block exclusive scan over <=512 values
__global__ void k_scan2(const int* __restrict__ in, int* __restrict__ out, int nb) {
  __shared__ int s[512];
  int t = threadIdx.x;
  int v = (t < nb) ? in[t] : 0;
  s[t] = v;
  __syncthreads();
  for (int d = 1; d < 512; d <<= 1) {
    int a = (t >= d) ? s[t - d] : 0;
    __syncthreads();
    s[t] += a;
    __syncthreads();
  }
  if (t < nb) out[t] = s[t] - v;
}

__global__ void k_scan3b(int* __restrict__ a, const int* __restrict__ bpref, int n) {
  int i = blockIdx.x * blockDim.x + threadIdx.x;
  if (i < n) a[i] += bpref[i >> 8];
}

// fp16 gather-reduce for F=16 rows (32B): 2 lanes/node, uint4 per lane, unroll 8.
template <bool BR, bool PSOUT>
__global__ void k_agg16h(const unsigned int* __restrict__ h, const int* __restrict__ csr,
                         const int* __restrict__ offs, const int* __restrict__ count,
                         const float* __restrict__ dinv, const float* __restrict__ bias,
                         unsigned int* __restrict__ out) {
  int wave = threadIdx.x >> 6, lane = threadIdx.x & 63;
  int i = (blockIdx.x * 4 + wave) * 32 + (lane >> 1);
  int q = lane & 1;  // uint4 half of the 8-uint row
  if (i >= NN) return;
  int off = offs[i], cnt = count[i];
  float di = dinv[i];
  float acc[8] = {0.f, 0.f, 0.f, 0.f, 0.f, 0.f, 0.f, 0.f};
  int j = 0;
  for (; j + 7 < cnt; j += 8) {
    int s0 = csr[off + j], s1 = csr[off + j + 1];
    int s2 = csr[off + j + 2], s3 = csr[off + j + 3];
    int s4 = csr[off + j + 4], s5 = csr[off + j + 5];
    int s6 = csr[off + j + 6], s7 = csr[off + j + 7];
    uint4 r0 = ((const uint4*)(h + (size_t)s0 * 8))[q];
    uint4 r1 = ((const uint4*)(h + (size_t)s1 * 8))[q];
    uint4 r2 = ((const uint4*)(h + (size_t)s2 * 8))[q];
    uint4 r3 = ((const uint4*)(h + (size_t)s3 * 8))[q];
    uint4 r4 = ((const uint4*)(h + (size_t)s4 * 8))[q];
    uint4 r5 = ((const uint4*)(h + (size_t)s5 * 8))[q];
    uint4 r6 = ((const uint4*)(h + (size_t)s6 * 8))[q];
    uint4 r7 = ((const uint4*)(h + (size_t)s7 * 8))[q];
    acc8(acc, r0); acc8(acc, r1); acc8(acc, r2); acc8(acc, r3);
    acc8(acc, r4); acc8(acc, r5); acc8(acc, r6); acc8(acc, r7);
  }
  for (; j < cnt; ++j) {
    uint4 r0 = ((const uint4*)(h + (size_t)csr[off + j] * 8))[q];
    acc8(acc, r0);
  }
  uint4 rs = ((const uint4*)(h + (size_t)i * 8))[q];  // self loop (prescaled)
  acc8(acc, rs);
  float v[8];
#pragma unroll
  for (int t = 0; t < 8; ++t) {
    v[t] = acc[t] * di;
    if (BR) v[t] = fmaxf(v[t] + bias[q * 8 + t], 0.f);
    if (PSOUT) v[t] *= di;
  }
  uint4 o;
  o.x = pack_f16(v[0], v[1]);
  o.y = pack_f16(v[2], v[3]);
  o.z = pack_f16(v[4], v[5]);
  o.w = pack_f16(v[6], v[7]);
  ((uint4*)(out + (size_t)i * 8))[q] = o;
}

// fp8 gather-reduce F=64 (64B rows): 4 lanes/node, uint4 (16 fp8) per lane, unroll 4.
// Output t3h in fp16.
__global__ void k_agg_b64f8(const unsigned int* __restrict__ h, const int* __restrict__ csr,
                            const int* __restrict__ offs, const int* __restrict__ count,
                            const float* __restrict__ dinv, unsigned int* __restrict__ out) {
  int wave = threadIdx.x >> 6, lane = threadIdx.x & 63;
  int i = (blockIdx.x * 4 + wave) * 16 + (lane >> 2);
  int q = lane & 3;  // uint4 index within 16-uint fp8 row
  if (i >= NN) return;
  int off = offs[i], cnt = count[i];
  float di = dinv[i];
  float acc[16];
#pragma unroll
  for (int t = 0; t < 16; ++t) acc[t] = 0.f;
  int j = 0;
  for (; j + 3 < cnt; j += 4) {
    int s0 = csr[off + j], s1 = csr[off + j + 1];
    int s2 = csr[off + j + 2], s3 = csr[off + j + 3];
    uint4 r0 = ((const uint4*)(h + (size_t)s0 * 16))[q];
    uint4 r1 = ((const uint4*)(h + (size_t)s1 * 16))[q];
    uint4 r2 = ((const uint4*)(h + (size_t)s2 * 16))[q];
    uint4 r3 = ((const uint4*)(h + (size_t)s3 * 16))[q];
#define DEC16(r)                                                            \
  {                                                                         \
    accf8(acc + 0, r.x);                                                    \
    accf8(acc + 4, r.y);                                                    \
    accf8(acc + 8, r.z);                                                    \
    accf8(acc + 12, r.w);                                                   \
  }
    DEC16(r0) DEC16(r1) DEC16(r2) DEC16(r3)
  }
  for (; j < cnt; ++j) {
    uint4 r0 = ((const uint4*)(h + (size_t)csr[off + j] * 16))[q];
    DEC16(r0)
  }
  uint4 rs = ((const uint4*)(h + (size_t)i * 16))[q];  // self loop (prescaled)
  DEC16(rs)
#undef DEC16
  // write 16 fp16 at feature offset q*16 -> uints [q*8, q*8+8)
  uint4 o0, o1;
  o0.x = pack_f16(acc[0] * di, acc[1] * di);
  o0.y = pack_f16(acc[2] * di, acc[3] * di);
  o0.z = pack_f16(acc[4] * di, acc[5] * di);
  o0.w = pack_f16(acc[6] * di, acc[7] * di);
  o1.x = pack_f16(acc[8] * di, acc[9] * di);
  o1.y = pack_f16(acc[10] * di, acc[11] * di);
  o1.z = pack_f16(acc[12] * di, acc[13] * di);
  o1.w = pack_f16(acc[14] * di, acc[15] * di);
  uint4* dst = (uint4*)(out + (size_t)i * 32 + q * 8);
  dst[0] = o0;
  dst[1] = o1;
}

// dense1: t1p = fp16((x@W1)*dinv); thread computes 2 packed outputs
__global__ void k_dense1_h(const float* __restrict__ x, const float* __restrict__ W,
                           const float* __restrict__ dinv, unsigned int* __restrict__ out,
                           int n) {
  __shared__ float sW[13 * 16];
  for (int t = threadIdx.x; t < 13 * 16; t += blockDim.x) sW[t] = W[t];
  __syncthreads();
  int idx = blockIdx.x * blockDim.x + threadIdx.x;
  int i = idx >> 3, u = idx & 7;
  if (i >= n) return;
  float a0 = 0.f, a1 = 0.f;
#pragma unroll
  for (int k = 0; k < 13; ++k) {
    float av = x[(size_t)i * 13 + k];
    a0 += av * sW[k * 16 + 2 * u];
    a1 += av * sW[k * 16 + 2 * u + 1];
  }
  float di = dinv[i];
  out[(size_t)i * 8 + u] = pack_f16(a0 * di, a1 * di);
}

// dense2: h2f8 = fp8(relu(t2@W2+b2)*di); fp16-packed input rows; 4 outputs/thread
__global__ void k_dense2_f8(const unsigned int* __restrict__ a, const float* __restrict__ W,
                            const float* __restrict__ b, const float* __restrict__ dinv,
                            unsigned int* __restrict__ out, int n) {
  __shared__ float sW[16 * 64];
  __shared__ float sb[64];
  for (int t = threadIdx.x; t < 16 * 64; t += blockDim.x) sW[t] = W[t];
  for (int t = threadIdx.x; t < 64; t += blockDim.x) sb[t] = b[t];
  __syncthreads();
  int idx = blockIdx.x * blockDim.x + threadIdx.x;
  int i = idx >> 4, g4 = idx & 15;  // group of 4 output features
  if (i >= n) return;
  float av[16];
#pragma unroll
  for (int u = 0; u < 8; ++u) {
    float2 p = unpack_f16(a[(size_t)i * 8 + u]);
    av[2 * u] = p.x;
    av[2 * u + 1] = p.y;
  }
  float acc[4];
#pragma unroll
  for (int ko = 0; ko < 4; ++ko) acc[ko] = sb[4 * g4 + ko];
#pragma unroll
  for (int k = 0; k < 16; ++k) {
#pragma unroll
    for (int ko = 0; ko < 4; ++ko) acc[ko] += av[k] * sW[k * 64 + 4 * g4 + ko];
  }
  float di = dinv[i];
#pragma unroll
  for (int ko = 0; ko < 4; ++ko) acc[ko] = fmaxf(acc[ko], 0.f) * di;
  unsigned int u = 0;
  u = __builtin_amdgcn_cvt_pk_fp8_f32(acc[0], acc[1], u, false);
  u = __builtin_amdgcn_cvt_pk_fp8_f32(acc[2], acc[3], u, true);
  out[(size_t)i * 16 + g4] = u;
}

// fused dense3(64->128)+relu+segmented mean-pool; NO LDS; fp16 input rows.
#define P4_NPW 16
__global__ __launch_bounds__(256) void k_dense3_pool4(
    const unsigned int* __restrict__ t3h, const float* __restrict__ W3,
    const float* __restrict__ b3, const int* __restrict__ batch,
    float* __restrict__ gsum) {
  int wu = blockIdx.x * 4 + (threadIdx.x >> 6);
  int lane = threadIdx.x & 63;
  int run = wu >> 1;
  int o = (wu & 1) * 64 + lane;
  int n0 = run * P4_NPW;
  if (n0 >= NN) return;
  float wcol[64];
#pragma unroll
  for (int k = 0; k < 64; ++k) wcol[k] = W3[k * 128 + o];
  float bias = b3[o];
  float acc = 0.f;
  int curg = -1;
#pragma unroll 1
  for (int j = 0; j < P4_NPW; ++j) {
    int n = n0 + j;
    if (n >= NN) break;
    int nu = __builtin_amdgcn_readfirstlane(n);
    const uint4* row = (const uint4*)(t3h + (size_t)nu * 32);
    float v = bias;
#pragma unroll
    for (int q = 0; q < 8; ++q) {
      uint4 r = row[q];
      float2 p0 = unpack_f16(r.x), p1 = unpack_f16(r.y);
      float2 p2 = unpack_f16(r.z), p3 = unpack_f16(r.w);
      v += p0.x * wcol[8 * q] + p0.y * wcol[8 * q + 1] + p1.x * wcol[8 * q + 2] +
           p1.y * wcol[8 * q + 3] + p2.x * wcol[8 * q + 4] + p2.y * wcol[8 * q + 5] +
           p3.x * wcol[8 * q + 6] + p3.y * wcol[8 * q + 7];
    }
    int g = batch[nu];
    if (g != curg) {
      if (curg >= 0) atomicAdd(&gsum[curg * 128 + o], acc);
      curg = g;
      acc = 0.f;
    }
    acc += fmaxf(v, 0.f);
  }
  if (curg >= 0) atomicAdd(&gsum[curg * 128 + o], acc);
}

// one wave per graph: logits = (gsum/cnt) @ Wl + bl; log_softmax over 16 classes
__global__ void k_head(const float* __restrict__ gsum, const int* __restrict__ gstart,
                       const float* __restrict__ Wl, const float* __restrict__ bl,
                       float* __restrict__ out) {
  int wave = threadIdx.x >> 6, lane = threadIdx.x & 63;
  int g = blockIdx.x * 4 + wave;
  if (g >= NG) return;
  int c = lane & 15, part = lane >> 4;
  float acc = 0.f;
#pragma unroll
  for (int kk = 0; kk < 32; ++kk) {
    int k = part * 32 + kk;
    acc += gsum[g * 128 + k] * Wl[k * NC + c];
  }
  acc += __shfl_xor(acc, 16);
  acc += __shfl_xor(acc, 32);
  int cnt = gstart[g + 1] - gstart[g];
  float inv = 1.0f / (float)max(cnt, 1);
  float logit = acc * inv + bl[c];
  float m = logit;
#pragma unroll
  for (int d = 1; d < 16; d <<= 1) m = fmaxf(m, __shfl_xor(m, d));
  float ex = expf(logit - m), s = ex;
#pragma unroll
  for (int d = 1; d < 16; d <<= 1) s += __shfl_xor(s, d);
  if (lane < 16) out[g * NC + lane] = logit - m - logf(s);
}

extern "C" void kernel_launch(void* const* d_in, const int* in_sizes, int n_in,
                              void* d_out, int out_size, void* d_ws, size_t ws_size,
                              hipStream_t stream) {
  const float* x = (const float*)d_in[0];
  const int* ei = (const int*)d_in[1];
  const int* batch = (const int*)d_in[2];
  const float* W1 = (const float*)d_in[3];
  const float* b1 = (const float*)d_in[4];
  const float* W2 = (const float*)d_in[5];
  const float* b2 = (const float*)d_in[6];
  const float* W3 = (const float*)d_in[7];
  const float* b3 = (const float*)d_in[8];
  const float* Wl = (const float*)d_in[9];
  const float* bl = (const float*)d_in[10];
  const int* src = ei;
  const int* dst = ei + NE;

  // workspace layout (~46 MB)
  int* bcnt = (int*)d_ws;                        // NBUK*NB1 = 76636 (scanned in place)
  int* bsum = bcnt + NBUK * NB1;                 // 1024
  int* bpref = bsum + 1024;                      // 1024
  int* gstart = bpref + 1024;                    // NG+2
  int* count = gstart + NG + 2;                  // NN
  int* offs = count + NN;                        // NN
  float* dinv = (float*)(offs + NN);             // NN
  float* gsum = (float*)(dinv + NN);             // NG*128
  unsigned int* packed = (unsigned int*)(gsum + NG * 128);  // NE
  int* csr = (int*)(packed + NE);                // NE (src only, 4B)
  unsigned int* t1p = (unsigned int*)(csr + NE); // NN*8 (fp16x2, prescaled)
  unsigned int* h1p = t1p + (size_t)NN * 8;      // NN*8 (fp16x2, prescaled)
  unsigned int* t2p = h1p + (size_t)NN * 8;      // NN*8 (fp16x2)
  unsigned int* h2f8 = t2p + (size_t)NN * 8;     // NN*16 (fp8x4, prescaled)
  unsigned int* t3h = h2f8 + (size_t)NN * 16;    // NN*32 (fp16x2)

  const int B = 256;
  const int NSC = NBUK * NB1;  // 76636

  // CSR build: two-level bucket sort, LDS atomics only
  k_zero_i<<<cdiv(NG * 128, B), B, 0, stream>>>((int*)gsum, NG * 128);
  k_p1a<<<NB1, 256, 0, stream>>>(dst, bcnt);
  k_bounds<<<cdiv(NN + 1, B), B, 0, stream>>>(batch, gstart);
  k_scan1<<<cdiv(NSC, 256), 256, 0, stream>>>(bcnt, bcnt, bsum, NSC);
  k_scan2<<<1, 512, 0, stream>>>(bsum, bpref, cdiv(NSC, 256));
  k_scan3b<<<cdiv(NSC, B), B, 0, stream>>>(bcnt, bpref, NSC);
  k_p1b<<<NB1, 256, 0, stream>>>(src, dst, bcnt, packed);
  k_p2<<<NBUK, 256, 0, stream>>>(packed, bcnt, count, offs, dinv, csr);

  // layer 1: t1p = fp16((x@W1)*di); h1p = fp16(relu(sum*di + b1)*di)
  k_dense1_h<<<cdiv((long long)NN * 8, B), B, 0, stream>>>(x, W1, dinv, t1p, NN);
  k_agg16h<true, true><<<cdiv(NN, 128), B, 0, stream>>>(
      t1p, csr, offs, count, dinv, b1, h1p);
  // layer 2: t2p = fp16(sum(h1p)*di); h2f8 = fp8(relu(t2@W2+b2)*di)
  k_agg16h<false, false><<<cdiv(NN, 128), B, 0, stream>>>(
      h1p, csr, offs, count, dinv, nullptr, t2p);
  k_dense2_f8<<<cdiv((long long)NN * 16, B), B, 0, stream>>>(t2p, W2, b2, dinv, h2f8, NN);
  // layer 3: t3h = fp16(sum_fp8(h2f8)*di); fused dense(64->128)+relu+pool
  k_agg_b64f8<<<cdiv(NN, 64), B, 0, stream>>>(h2f8, csr, offs, count, dinv, t3h);
  {
    int runs = cdiv(NN, P4_NPW);
    k_dense3_pool4<<<cdiv(runs * 2, 4), 256, 0, stream>>>(t3h, W3, b3, batch, gsum);
  }

  // head
  k_head<<<NG / 4, B, 0, stream>>>(gsum, gstart, Wl, bl, (float*)d_out);
}